// Round 8
// baseline (119.130 us; speedup 1.0000x reference)
//
#include <hip/hip_runtime.h>
#include <math.h>

#define DIM    256
#define NHEAD  32
#define HDIM   8
#define KTOP   512
#define NTOK   4096   // 16*16*16
#define NB     2

typedef float    f32x4  __attribute__((ext_vector_type(4)));
typedef _Float16 f16x8  __attribute__((ext_vector_type(8)));
typedef __fp16   h16x2  __attribute__((ext_vector_type(2)));   // cvt_pkrtz return type
typedef f16x8 f16x8a __attribute__((may_alias));
typedef int4  aint4  __attribute__((may_alias));
typedef uint2 auint2 __attribute__((may_alias));

// ---------------- workspace layout (floats) ----------------
#define AM_OFF   0                               // [B][2][NTOK] avg/max
#define SC_OFF   16384                           // [B][NTOK] scores
#define IDX_OFF  24576                           // [B][KTOP] ints
#define QKV_OFF  25600                           // [B][NTOK][768] (q part unused)
#define VT_OFF   (25600 + 6291456)               // [B][DIM][NTOK] v transposed
#define AT_OFF   (VT_OFF + 2097152)              // [B][DIM][NTOK] attn out (c-major)
#define DW_OFF   (AT_OFF + 2097152)              // [B][DIM][NTOK] dwconv out
#define KVS_OFF  (DW_OFF + 2097152)              // [B][32][512][16] f16 K/V (1MB)
#define QH_OFF   (KVS_OFF + 262144)              // [B][32][NTOK][8] q head-major

// ---------------- 2. 7x7x7 conv (2->1 ch) + sigmoid, LDS-staged ----------------
__global__ __launch_bounds__(256)
void spa_conv(const float* __restrict__ am, const float* __restrict__ w,
              float* __restrict__ scores) {
    __shared__ float tile[2][7][22][24];   // 28.9 KB
    __shared__ float red[4][256];
    int bd = blockIdx.x;          // b*16 + d
    int b = bd >> 4, d = bd & 15;
    int tid = threadIdx.x;
    float4* t4 = (float4*)&tile[0][0][0][0];
    for (int i = tid; i < (2 * 7 * 22 * 24) / 4; i += 256)
        t4[i] = (float4){0.f, 0.f, 0.f, 0.f};
    __syncthreads();
    for (int it = 0; it < 14; ++it) {
        int j = it * 256 + tid;
        int ci = (j >= 1792) ? 1 : 0;
        int r = j - ci * 1792;
        int kd = r >> 8, pos = r & 255;
        int dz = d + kd - 3;
        if ((unsigned)dz < 16u)
            tile[ci][kd][(pos >> 4) + 3][(pos & 15) + 3] =
                am[((size_t)b * 2 + ci) * NTOK + dz * 256 + pos];
    }
    __syncthreads();
    int h  = (tid >> 2) & 15;
    int wg = tid & 3;
    int s  = __builtin_amdgcn_readfirstlane(tid >> 6);
    int pstart = (s < 2) ? s * 4 : 8 + (s - 2) * 3;
    int pcnt   = (s < 2) ? 4 : 3;
    float o0 = 0.f, o1 = 0.f, o2 = 0.f, o3 = 0.f;
    for (int pp = 0; pp < 4; ++pp) {
        if (pp >= pcnt) break;
        int p = pstart + pp;
        int ci = (p >= 7) ? 1 : 0;
        int kd = p - ci * 7;
        const float* wrow = w + (ci * 343 + kd * 49);
#pragma unroll
        for (int kh = 0; kh < 7; ++kh) {
            const float* trow = &tile[ci][kd][h + kh][wg * 4];
            float4 r0 = *(const float4*)(trow);
            float4 r1 = *(const float4*)(trow + 4);
            float4 r2 = *(const float4*)(trow + 8);
            float rr[12] = {r0.x, r0.y, r0.z, r0.w, r1.x, r1.y, r1.z, r1.w,
                            r2.x, r2.y, r2.z, r2.w};
#pragma unroll
            for (int kw = 0; kw < 7; ++kw) {
                float wv = wrow[kh * 7 + kw];
                o0 += rr[kw + 0] * wv;
                o1 += rr[kw + 1] * wv;
                o2 += rr[kw + 2] * wv;
                o3 += rr[kw + 3] * wv;
            }
        }
    }
    int q = h * 16 + wg * 4;
    red[s][q + 0] = o0; red[s][q + 1] = o1; red[s][q + 2] = o2; red[s][q + 3] = o3;
    __syncthreads();
    float acc = red[0][tid] + red[1][tid] + red[2][tid] + red[3][tid];
    float sg = 1.0f / (1.0f + expf(-acc));
    scores[(size_t)b * NTOK + d * 256 + tid] = sg;
}

// ---------------- 3. top-512 SET selection (register-cached radix) ----------------
__global__ __launch_bounds__(256)
void topk_select(const float* __restrict__ scores, int* __restrict__ idx) {
    __shared__ int wsum[4];
    __shared__ unsigned int s_thr;
    __shared__ int s_cnt;
    __shared__ unsigned int tiem[NTOK / 32];
    __shared__ int tiep[NTOK / 32];
    int b = blockIdx.x, tid = threadIdx.x;
    int lane = tid & 63, wid = tid >> 6;
    unsigned int v[16];
#pragma unroll
    for (int j = 0; j < 16; ++j)
        v[j] = __float_as_uint(scores[b * NTOK + j * 256 + tid]);  // positive, <1.0
    if (tid == 0) { s_thr = 0u; s_cnt = 0; }
    if (tid < NTOK / 32) tiem[tid] = 0u;
    __syncthreads();
    for (int bit = 29; bit >= 0; --bit) {
        unsigned int test = s_thr | (1u << bit);
        int c = 0;
#pragma unroll
        for (int j = 0; j < 16; ++j)
            c += (int)__popcll(__ballot(v[j] >= test));
        if (lane == 0) wsum[wid] = c;
        __syncthreads();
        if (tid == 0) {
            int tot = wsum[0] + wsum[1] + wsum[2] + wsum[3];
            if (tot >= KTOP) s_thr = test;
        }
        __syncthreads();
    }
    unsigned int T = s_thr;
    {
        int c = 0;
#pragma unroll
        for (int j = 0; j < 16; ++j)
            c += (int)__popcll(__ballot(v[j] > T));
        if (lane == 0) wsum[wid] = c;
    }
    __syncthreads();
    int cnt_gt = wsum[0] + wsum[1] + wsum[2] + wsum[3];
    int krem = KTOP - cnt_gt;
#pragma unroll
    for (int j = 0; j < 16; ++j) {
        int i = j * 256 + tid;
        if (v[j] > T) {
            int p = atomicAdd(&s_cnt, 1);
            idx[b * KTOP + p] = i;
        }
        if (v[j] == T) atomicOr(&tiem[i >> 5], 1u << (i & 31));
    }
    __syncthreads();
    if (tid == 0) {
        int c = 0;
        for (int w2 = 0; w2 < NTOK / 32; ++w2) { tiep[w2] = c; c += __popc(tiem[w2]); }
    }
    __syncthreads();
#pragma unroll
    for (int j = 0; j < 16; ++j) {
        int i = j * 256 + tid;
        if (v[j] == T) {
            int r = tiep[i >> 5] + __popc(tiem[i >> 5] & ((1u << (i & 31)) - 1u));
            if (r < krem) idx[b * KTOP + cnt_gt + r] = i;
        }
    }
}

// ---------------- 4. qkv MFMA GEMM (+fused channel mean/max for j0==0 blocks) ----
// grid (12 j, 64 n, B): j fastest -> consecutive blocks share the A n-tile in L2.
// j<256 (q): write head-major qh[b][h][n][8]. j>=256: write qo[n][768] row (k,v);
// j>=512 additionally vt[b][c][n]. blockIdx.x==0 blocks also reduce mean/max of
// the fp32 A values they stage (replaces reduce_am kernel).
__global__ __launch_bounds__(256)
void gemm_qkv(const float* __restrict__ A_, const float* __restrict__ W,
              float* __restrict__ qo, float* __restrict__ vt,
              float* __restrict__ qh, float* __restrict__ am) {
    __shared__ _Float16 Ws_h[64][72];
    __shared__ _Float16 Xs[64][72];
    __shared__ float ams[2][4][64];
    int b  = blockIdx.z;
    int j0 = blockIdx.x * 64;
    int n0 = blockIdx.y * 64;
    int t  = threadIdx.x;
    int lane = t & 63, wid = t >> 6;
    int wj = wid >> 1, wn = wid & 1;
    const float* A = A_ + (size_t)b * DIM * NTOK;
    bool do_am = (blockIdx.x == 0);

    f32x4 acc00 = {0.f,0.f,0.f,0.f}, acc01 = {0.f,0.f,0.f,0.f};
    f32x4 acc10 = {0.f,0.f,0.f,0.f}, acc11 = {0.f,0.f,0.f,0.f};
    float amsum = 0.f, ammax = -1e30f;

    for (int ks = 0; ks < 4; ++ks) {
        int c0 = ks * 64;
        if (ks) __syncthreads();
#pragma unroll
        for (int r = 0; r < 4; ++r) {
            int j  = r * 16 + (t >> 4);
            int cq = (t & 15) * 4;
            float4 wv = *(const float4*)(W + (size_t)(j0 + j) * DIM + c0 + cq);
            union { h16x2 h2[2]; uint2 u2; } p;
            p.h2[0] = __builtin_amdgcn_cvt_pkrtz(wv.x, wv.y);
            p.h2[1] = __builtin_amdgcn_cvt_pkrtz(wv.z, wv.w);
            *(auint2*)&Ws_h[j][cq] = p.u2;
        }
        {
            int nl = t & 63, cb = (t >> 6) * 16;
            float v[16];
#pragma unroll
            for (int i = 0; i < 16; ++i)
                v[i] = A[(size_t)(c0 + cb + i) * NTOK + n0 + nl];
            if (do_am) {
#pragma unroll
                for (int i = 0; i < 16; ++i) {
                    amsum += v[i]; ammax = fmaxf(ammax, v[i]);
                }
            }
            union { h16x2 h2[8]; int4 i4[2]; } u;
#pragma unroll
            for (int m = 0; m < 8; ++m)
                u.h2[m] = __builtin_amdgcn_cvt_pkrtz(v[2 * m], v[2 * m + 1]);
            *(aint4*)&Xs[nl][cb]     = u.i4[0];
            *(aint4*)&Xs[nl][cb + 8] = u.i4[1];
        }
        __syncthreads();
        const _Float16* wA = &Ws_h[wj * 32 + (lane & 15)][(lane >> 4) * 8];
        const _Float16* xB = &Xs [wn * 32 + (lane & 15)][(lane >> 4) * 8];
#pragma unroll
        for (int s = 0; s < 2; ++s) {
            f16x8 a0  = *(const f16x8a*)(wA + s * 32);
            f16x8 a1  = *(const f16x8a*)(wA + 16 * 72 + s * 32);
            f16x8 b0v = *(const f16x8a*)(xB + s * 32);
            f16x8 b1v = *(const f16x8a*)(xB + 16 * 72 + s * 32);
            acc00 = __builtin_amdgcn_mfma_f32_16x16x32_f16(a0, b0v, acc00, 0, 0, 0);
            acc01 = __builtin_amdgcn_mfma_f32_16x16x32_f16(a0, b1v, acc01, 0, 0, 0);
            acc10 = __builtin_amdgcn_mfma_f32_16x16x32_f16(a1, b0v, acc10, 0, 0, 0);
            acc11 = __builtin_amdgcn_mfma_f32_16x16x32_f16(a1, b1v, acc11, 0, 0, 0);
        }
    }

    if (do_am) {
        int nl = t & 63, cbg = t >> 6;
        ams[0][cbg][nl] = amsum;
        ams[1][cbg][nl] = ammax;
        __syncthreads();
        if (t < 64) {
            float ss = (ams[0][0][t] + ams[0][1][t]) + (ams[0][2][t] + ams[0][3][t]);
            float mm = fmaxf(fmaxf(ams[1][0][t], ams[1][1][t]),
                             fmaxf(ams[1][2][t], ams[1][3][t]));
            am[(size_t)b * 2 * NTOK + n0 + t]        = ss * (1.0f / DIM);
            am[(size_t)b * 2 * NTOK + NTOK + n0 + t] = mm;
        }
    }

    int jb0 = j0 + wj * 32 + (lane >> 4) * 4;
    int nn0 = n0 + wn * 32 + (lane & 15);
#pragma unroll
    for (int jt = 0; jt < 2; ++jt) {
#pragma unroll
        for (int nt = 0; nt < 2; ++nt) {
            f32x4 ac = (jt == 0) ? (nt == 0 ? acc00 : acc01)
                                 : (nt == 0 ? acc10 : acc11);
            int jb = jb0 + jt * 16;
            int n  = nn0 + nt * 16;
            if (jb < 256) {
                int hh = jb >> 3, dq = jb & 7;
                float4 vv = {ac[0], ac[1], ac[2], ac[3]};
                *(float4*)(qh + ((size_t)((b << 5) | hh) * NTOK + n) * 8 + dq) = vv;
            } else {
                float* qrow = qo + (size_t)b * NTOK * 768;
                float4 vv = {ac[0], ac[1], ac[2], ac[3]};
                *(float4*)(qrow + (size_t)n * 768 + jb) = vv;
                if (jb >= 512) {
                    float* vp = vt + (size_t)(b * DIM + jb - 512) * NTOK + n;
                    vp[0] = ac[0]; vp[NTOK] = ac[1];
                    vp[2 * NTOK] = ac[2]; vp[3 * NTOK] = ac[3];
                }
            }
        }
    }
}

// ---------------- 4b. stage gathered K/V once per (b,h) -> packed f16 ----------
__global__ __launch_bounds__(256)
void kv_stage(const float* __restrict__ qkv, const int* __restrict__ idx,
              _Float16* __restrict__ kvs) {
    int bh = blockIdx.x;              // b*32 + h
    int h = bh & 31, b = bh >> 5;
    int tid = threadIdx.x;
    const float* qkvb = qkv + (size_t)b * NTOK * 768;
    const int* ib = idx + b * KTOP;
    aint4* dst = (aint4*)(kvs + (size_t)bh * KTOP * 16);
    for (int i = tid; i < KTOP; i += 256) {
        int tok = ib[i];
        const float* kp = qkvb + (size_t)tok * 768 + DIM + h * HDIM;
        float4 k0 = *(const float4*)kp,          k1 = *(const float4*)(kp + 4);
        float4 v0 = *(const float4*)(kp + DIM),  v1 = *(const float4*)(kp + DIM + 4);
        union { h16x2 h2[4]; int4 i4; } kk, vv;
        kk.h2[0] = __builtin_amdgcn_cvt_pkrtz(k0.x, k0.y);
        kk.h2[1] = __builtin_amdgcn_cvt_pkrtz(k0.z, k0.w);
        kk.h2[2] = __builtin_amdgcn_cvt_pkrtz(k1.x, k1.y);
        kk.h2[3] = __builtin_amdgcn_cvt_pkrtz(k1.z, k1.w);
        vv.h2[0] = __builtin_amdgcn_cvt_pkrtz(v0.x, v0.y);
        vv.h2[1] = __builtin_amdgcn_cvt_pkrtz(v0.z, v0.w);
        vv.h2[2] = __builtin_amdgcn_cvt_pkrtz(v1.x, v1.y);
        vv.h2[3] = __builtin_amdgcn_cvt_pkrtz(v1.z, v1.w);
        dst[2 * i]     = kk.i4;
        dst[2 * i + 1] = vv.i4;
    }
}

// ---------------- 5. attention via MFMA (f16 fragments, fp32 accumulate) --------
__global__ __launch_bounds__(256)
void attn_mfma(const float* __restrict__ qh, const _Float16* __restrict__ kvs,
               float* __restrict__ at) {
    __shared__ _Float16 Klds[KTOP][8];        // [k][d]           16B rows
    __shared__ _Float16 Vt[8][KTOP + 8];      // [d][k] pad row   (2-way max)
    __shared__ _Float16 Plds[4][16 * 40];     // per-wave [q][40] (2-way max)
    int blk = blockIdx.x;                     // ((b*32+h)*16 + tb)
    int tb = blk & 15, h = (blk >> 4) & 31, b = blk >> 9;
    int tid = threadIdx.x, lane = tid & 63, wid = tid >> 6;

    // ---- linear load of staged K/V -> LDS ----
    const aint4* kvb = (const aint4*)(kvs + (size_t)((b << 5) | h) * KTOP * 16);
    for (int i = tid; i < KTOP; i += 256) {
        int4 kk = kvb[2 * i];
        int4 vv = kvb[2 * i + 1];
        *(aint4*)&Klds[i][0] = kk;
        union { int4 i4; unsigned short u[8]; } uv; uv.i4 = vv;
        unsigned short* vcol = (unsigned short*)&Vt[0][0];
#pragma unroll
        for (int d = 0; d < 8; ++d)
            vcol[d * (KTOP + 8) + i] = uv.u[d];
    }

    // ---- Q fragments from head-major qh (coalesced 32B/token) ----
    const float qsc = 0.35355339059327373f * 1.4426950408889634f;
    int qblk = tb * 256 + wid * 64;
    int qcol = lane & 15;
    const float* qb = qh + (size_t)((b << 5) | h) * NTOK * 8;
    f16x8 qf[4];
#pragma unroll
    for (int t = 0; t < 4; ++t) {
        const float* qp = qb + (size_t)(qblk + t * 16 + qcol) * 8;
        float4 a0 = *(const float4*)qp, a1 = *(const float4*)(qp + 4);
        union { h16x2 h2[4]; f16x8 v; } u;
        u.h2[0] = __builtin_amdgcn_cvt_pkrtz(a0.x * qsc, a0.y * qsc);
        u.h2[1] = __builtin_amdgcn_cvt_pkrtz(a0.z * qsc, a0.w * qsc);
        u.h2[2] = __builtin_amdgcn_cvt_pkrtz(a1.x * qsc, a1.y * qsc);
        u.h2[3] = __builtin_amdgcn_cvt_pkrtz(a1.z * qsc, a1.w * qsc);
        qf[t] = u.v;
    }
    __syncthreads();

    int g = lane >> 4;
    _Float16* pw = &Plds[wid][(lane & 15) * 40 + g * 4];
    const f16x8a* pr = (const f16x8a*)&Plds[wid][(lane & 15) * 40 + g * 8];
    const _Float16* vrow = &Vt[lane & 7][g * 8];

    f32x4 acc[4];
    float lsum[4] = {0.f, 0.f, 0.f, 0.f};
#pragma unroll
    for (int t = 0; t < 4; ++t) acc[t] = (f32x4){0.f, 0.f, 0.f, 0.f};
    const f32x4 z = {0.f, 0.f, 0.f, 0.f};

    for (int ks = 0; ks < 16; ++ks) {
        f16x8 ka = {}, kb = {};
        if (lane < 16) {
            ka = *(const f16x8a*)&Klds[ks * 32 + lane][0];
            kb = *(const f16x8a*)&Klds[ks * 32 + 16 + lane][0];
        }
        f16x8 vf = *(const f16x8a*)&vrow[ks * 32];
#pragma unroll
        for (int t = 0; t < 4; ++t) {
            f32x4 c0 = __builtin_amdgcn_mfma_f32_16x16x32_f16(ka, qf[t], z, 0, 0, 0);
            f32x4 c1 = __builtin_amdgcn_mfma_f32_16x16x32_f16(kb, qf[t], z, 0, 0, 0);
            float p0 = __builtin_amdgcn_exp2f(c0[0]);
            float p1 = __builtin_amdgcn_exp2f(c0[1]);
            float p2 = __builtin_amdgcn_exp2f(c0[2]);
            float p3 = __builtin_amdgcn_exp2f(c0[3]);
            float p4 = __builtin_amdgcn_exp2f(c1[0]);
            float p5 = __builtin_amdgcn_exp2f(c1[1]);
            float p6 = __builtin_amdgcn_exp2f(c1[2]);
            float p7 = __builtin_amdgcn_exp2f(c1[3]);
            lsum[t] += ((p0 + p1) + (p2 + p3)) + ((p4 + p5) + (p6 + p7));
            union { h16x2 h2[2]; uint2 u2; } w01, w23;
            w01.h2[0] = __builtin_amdgcn_cvt_pkrtz(p0, p1);
            w01.h2[1] = __builtin_amdgcn_cvt_pkrtz(p2, p3);
            w23.h2[0] = __builtin_amdgcn_cvt_pkrtz(p4, p5);
            w23.h2[1] = __builtin_amdgcn_cvt_pkrtz(p6, p7);
            *(auint2*)pw        = w01.u2;     // tile0 rows g*4..+3
            *(auint2*)(pw + 16) = w23.u2;     // tile1 rows 16+g*4..+3
            f16x8 pf = *pr;                   // B-frag: rows g*8..+7, col q
            acc[t] = __builtin_amdgcn_mfma_f32_16x16x32_f16(vf, pf, acc[t], 0, 0, 0);
        }
    }

    // ---- epilogue: normalize by row-sum, write O (c-major) ----
#pragma unroll
    for (int t = 0; t < 4; ++t) {
        float ls = lsum[t];
        ls += __shfl_xor(ls, 16);
        ls += __shfl_xor(ls, 32);
        float inv = 1.0f / ls;
        if (lane < 32) {
            int n = qblk + t * 16 + (lane & 15);
            int dbase = (lane >> 4) * 4;
            float* op = at + ((size_t)(b * DIM + h * HDIM + dbase)) * NTOK + n;
            op[0]            = acc[t][0] * inv;
            op[NTOK]         = acc[t][1] * inv;
            op[2 * NTOK]     = acc[t][2] * inv;
            op[3 * NTOK]     = acc[t][3] * inv;
        }
    }
}

// ---------------- 7. depthwise 3x3x3 conv ----------------
__global__ __launch_bounds__(256)
void dw_conv(const float* __restrict__ vt, const float* __restrict__ dww,
             const float* __restrict__ dwb, float* __restrict__ out) {
    __shared__ float tile[NTOK];     // 16 KB, one (b,c) volume
    int bc = blockIdx.x;             // b*DIM + c
    int b = bc / DIM, c = bc % DIM;
    int tid = threadIdx.x;
    const float* src = vt + (size_t)(b * DIM + c) * NTOK;
    for (int i = tid; i < NTOK; i += 256) tile[i] = src[i];
    float wreg[27];
#pragma unroll
    for (int i = 0; i < 27; ++i) wreg[i] = dww[c * 27 + i];
    float bias = dwb[c];
    __syncthreads();
    for (int i = tid; i < NTOK; i += 256) {
        int d = i >> 8, h = (i >> 4) & 15, w = i & 15;
        float acc = bias;
#pragma unroll
        for (int kd = 0; kd < 3; ++kd) {
            int dz = d + kd - 1; if (dz < 0 || dz > 15) continue;
#pragma unroll
            for (int kh = 0; kh < 3; ++kh) {
                int hz = h + kh - 1; if (hz < 0 || hz > 15) continue;
#pragma unroll
                for (int kw = 0; kw < 3; ++kw) {
                    int wz = w + kw - 1; if (wz < 0 || wz > 15) continue;
                    acc += tile[(dz * 16 + hz) * 16 + wz] * wreg[(kd * 3 + kh) * 3 + kw];
                }
            }
        }
        out[(size_t)(b * DIM + c) * NTOK + i] = acc;
    }
}

// ---------------- 6+8. fused proj + pw GEMM: out = proj(at)+pw(dw)+biases ------
// grid (4 j, 64 n, B), j fastest. Both products accumulate into the same acc.
__global__ __launch_bounds__(256)
void gemm_dual(const float* __restrict__ At, const float* __restrict__ Dw,
               const float* __restrict__ Wp_, const float* __restrict__ Wq_,
               const float* __restrict__ bp_, const float* __restrict__ bq_,
               float* __restrict__ outbase) {
    __shared__ _Float16 Wp[64][72];
    __shared__ _Float16 Wq[64][72];
    __shared__ _Float16 Xa[64][72];
    __shared__ _Float16 Xd[64][72];
    int b  = blockIdx.z;
    int j0 = blockIdx.x * 64;
    int n0 = blockIdx.y * 64;
    int t  = threadIdx.x;
    int lane = t & 63, wid = t >> 6;
    int wj = wid >> 1, wn = wid & 1;
    const float* Aa = At + (size_t)b * DIM * NTOK;
    const float* Ad = Dw + (size_t)b * DIM * NTOK;

    f32x4 acc00 = {0.f,0.f,0.f,0.f}, acc01 = {0.f,0.f,0.f,0.f};
    f32x4 acc10 = {0.f,0.f,0.f,0.f}, acc11 = {0.f,0.f,0.f,0.f};

    for (int ks = 0; ks < 4; ++ks) {
        int c0 = ks * 64;
        if (ks) __syncthreads();
#pragma unroll
        for (int r = 0; r < 4; ++r) {
            int j  = r * 16 + (t >> 4);
            int cq = (t & 15) * 4;
            float4 wv = *(const float4*)(Wp_ + (size_t)(j0 + j) * DIM + c0 + cq);
            float4 wu = *(const float4*)(Wq_ + (size_t)(j0 + j) * DIM + c0 + cq);
            union { h16x2 h2[2]; uint2 u2; } p, q;
            p.h2[0] = __builtin_amdgcn_cvt_pkrtz(wv.x, wv.y);
            p.h2[1] = __builtin_amdgcn_cvt_pkrtz(wv.z, wv.w);
            q.h2[0] = __builtin_amdgcn_cvt_pkrtz(wu.x, wu.y);
            q.h2[1] = __builtin_amdgcn_cvt_pkrtz(wu.z, wu.w);
            *(auint2*)&Wp[j][cq] = p.u2;
            *(auint2*)&Wq[j][cq] = q.u2;
        }
        {
            int nl = t & 63, cb = (t >> 6) * 16;
            float v[16];
#pragma unroll
            for (int i = 0; i < 16; ++i)
                v[i] = Aa[(size_t)(c0 + cb + i) * NTOK + n0 + nl];
            union { h16x2 h2[8]; int4 i4[2]; } u;
#pragma unroll
            for (int m = 0; m < 8; ++m)
                u.h2[m] = __builtin_amdgcn_cvt_pkrtz(v[2 * m], v[2 * m + 1]);
            *(aint4*)&Xa[nl][cb]     = u.i4[0];
            *(aint4*)&Xa[nl][cb + 8] = u.i4[1];
#pragma unroll
            for (int i = 0; i < 16; ++i)
                v[i] = Ad[(size_t)(c0 + cb + i) * NTOK + n0 + nl];
#pragma unroll
            for (int m = 0; m < 8; ++m)
                u.h2[m] = __builtin_amdgcn_cvt_pkrtz(v[2 * m], v[2 * m + 1]);
            *(aint4*)&Xd[nl][cb]     = u.i4[0];
            *(aint4*)&Xd[nl][cb + 8] = u.i4[1];
        }
        __syncthreads();
        const _Float16* wPa = &Wp[wj * 32 + (lane & 15)][(lane >> 4) * 8];
        const _Float16* wQa = &Wq[wj * 32 + (lane & 15)][(lane >> 4) * 8];
        const _Float16* xAa = &Xa[wn * 32 + (lane & 15)][(lane >> 4) * 8];
        const _Float16* xDa = &Xd[wn * 32 + (lane & 15)][(lane >> 4) * 8];
#pragma unroll
        for (int s = 0; s < 2; ++s) {
            f16x8 p0 = *(const f16x8a*)(wPa + s * 32);
            f16x8 p1 = *(const f16x8a*)(wPa + 16 * 72 + s * 32);
            f16x8 q0 = *(const f16x8a*)(wQa + s * 32);
            f16x8 q1 = *(const f16x8a*)(wQa + 16 * 72 + s * 32);
            f16x8 a0 = *(const f16x8a*)(xAa + s * 32);
            f16x8 a1 = *(const f16x8a*)(xAa + 16 * 72 + s * 32);
            f16x8 d0 = *(const f16x8a*)(xDa + s * 32);
            f16x8 d1 = *(const f16x8a*)(xDa + 16 * 72 + s * 32);
            acc00 = __builtin_amdgcn_mfma_f32_16x16x32_f16(p0, a0, acc00, 0, 0, 0);
            acc00 = __builtin_amdgcn_mfma_f32_16x16x32_f16(q0, d0, acc00, 0, 0, 0);
            acc01 = __builtin_amdgcn_mfma_f32_16x16x32_f16(p0, a1, acc01, 0, 0, 0);
            acc01 = __builtin_amdgcn_mfma_f32_16x16x32_f16(q0, d1, acc01, 0, 0, 0);
            acc10 = __builtin_amdgcn_mfma_f32_16x16x32_f16(p1, a0, acc10, 0, 0, 0);
            acc10 = __builtin_amdgcn_mfma_f32_16x16x32_f16(q1, d0, acc10, 0, 0, 0);
            acc11 = __builtin_amdgcn_mfma_f32_16x16x32_f16(p1, a1, acc11, 0, 0, 0);
            acc11 = __builtin_amdgcn_mfma_f32_16x16x32_f16(q1, d1, acc11, 0, 0, 0);
        }
    }

    int jb0 = j0 + wj * 32 + (lane >> 4) * 4;
    int nn0 = n0 + wn * 32 + (lane & 15);
#pragma unroll
    for (int jt = 0; jt < 2; ++jt) {
#pragma unroll
        for (int nt = 0; nt < 2; ++nt) {
            f32x4 ac = (jt == 0) ? (nt == 0 ? acc00 : acc01)
                                 : (nt == 0 ? acc10 : acc11);
            int jb = jb0 + jt * 16;
            int n  = nn0 + nt * 16;
            float4 bp = *(const float4*)(bp_ + jb);
            float4 bq = *(const float4*)(bq_ + jb);
            float* op = outbase + (size_t)(b * DIM + jb) * NTOK + n;
            op[0]        = ac[0] + bp.x + bq.x;
            op[NTOK]     = ac[1] + bp.y + bq.y;
            op[2 * NTOK] = ac[2] + bp.z + bq.z;
            op[3 * NTOK] = ac[3] + bp.w + bq.w;
        }
    }
}

extern "C" void kernel_launch(void* const* d_in, const int* in_sizes, int n_in,
                              void* d_out, int out_size, void* d_ws, size_t ws_size,
                              hipStream_t stream) {
    const float* x      = (const float*)d_in[0];
    const float* spa_w  = (const float*)d_in[1];
    const float* qkv_w  = (const float*)d_in[2];
    const float* proj_w = (const float*)d_in[3];
    const float* proj_b = (const float*)d_in[4];
    const float* dw_w   = (const float*)d_in[5];
    const float* dw_b   = (const float*)d_in[6];
    const float* pw_w   = (const float*)d_in[7];
    const float* pw_b   = (const float*)d_in[8];
    float* out = (float*)d_out;
    float* ws  = (float*)d_ws;

    float* am     = ws + AM_OFF;
    float* scores = ws + SC_OFF;
    int*   idx    = (int*)(ws + IDX_OFF);
    float* qkvbuf = ws + QKV_OFF;
    float* vtbuf  = ws + VT_OFF;
    float* atbuf  = ws + AT_OFF;
    float* dwbuf  = ws + DW_OFF;
    _Float16* kvs = (_Float16*)(ws + KVS_OFF);
    float* qhbuf  = ws + QH_OFF;

    gemm_qkv<<<dim3(12, 64, NB), 256, 0, stream>>>(x, qkv_w, qkvbuf, vtbuf, qhbuf, am);
    spa_conv<<<NB * 16, 256, 0, stream>>>(am, spa_w, scores);
    topk_select<<<NB, 256, 0, stream>>>(scores, idx);
    kv_stage<<<NB * NHEAD, 256, 0, stream>>>(qkvbuf, idx, kvs);
    attn_mfma<<<NB * NHEAD * 16, 256, 0, stream>>>(qhbuf, kvs, atbuf);
    dw_conv<<<NB * DIM, 256, 0, stream>>>(vtbuf, dw_w, dw_b, dwbuf);
    gemm_dual<<<dim3(4, 64, NB), 256, 0, stream>>>(atbuf, dwbuf, proj_w, pw_w,
                                                   proj_b, pw_b, out);
}

// Round 9
// 109.497 us; speedup vs baseline: 1.0880x; 1.0880x over previous
//
#include <hip/hip_runtime.h>
#include <math.h>

#define DIM    256
#define NHEAD  32
#define HDIM   8
#define KTOP   512
#define NTOK   4096   // 16*16*16
#define NB     2

typedef float    f32x4  __attribute__((ext_vector_type(4)));
typedef _Float16 f16x8  __attribute__((ext_vector_type(8)));
typedef __fp16   h16x2  __attribute__((ext_vector_type(2)));   // cvt_pkrtz return type
typedef f16x8 f16x8a __attribute__((may_alias));
typedef int4  aint4  __attribute__((may_alias));
typedef uint2 auint2 __attribute__((may_alias));

// ---------------- workspace layout (float offsets) ----------------
#define AM_OFF   0                         // [B][2][NTOK] avg/max
#define SC_OFF   16384                     // [B][NTOK] scores
#define VT_OFF   24576                     // [B][DIM][NTOK] v fp32 (c-major)
#define AT_OFF   (VT_OFF + 2097152)        // [B][DIM][NTOK] attn out
#define DW_OFF   (AT_OFF + 2097152)        // [B][DIM][NTOK] dwconv out
#define KVS_OFF  (DW_OFF + 2097152)        // [B*32][512][16] f16 gathered K/V
#define KHV_OFF  (KVS_OFF + 262144)        // [B][NTOK][512] f16 (k:0-255, v:256-511)
#define QH_OFF   (KHV_OFF + 2097152)       // [B*32][NTOK][8] f16 q pre-scaled

// ---------------- 2. 7x7x7 conv (2->1 ch) + sigmoid, LDS-staged ----------------
__global__ __launch_bounds__(256)
void spa_conv(const float* __restrict__ am, const float* __restrict__ w,
              float* __restrict__ scores) {
    __shared__ float tile[2][7][22][24];   // 28.9 KB
    __shared__ float red[4][256];
    int bd = blockIdx.x;          // b*16 + d
    int b = bd >> 4, d = bd & 15;
    int tid = threadIdx.x;
    float4* t4 = (float4*)&tile[0][0][0][0];
    for (int i = tid; i < (2 * 7 * 22 * 24) / 4; i += 256)
        t4[i] = (float4){0.f, 0.f, 0.f, 0.f};
    __syncthreads();
    for (int it = 0; it < 14; ++it) {
        int j = it * 256 + tid;
        int ci = (j >= 1792) ? 1 : 0;
        int r = j - ci * 1792;
        int kd = r >> 8, pos = r & 255;
        int dz = d + kd - 3;
        if ((unsigned)dz < 16u)
            tile[ci][kd][(pos >> 4) + 3][(pos & 15) + 3] =
                am[((size_t)b * 2 + ci) * NTOK + dz * 256 + pos];
    }
    __syncthreads();
    int h  = (tid >> 2) & 15;
    int wg = tid & 3;
    int s  = __builtin_amdgcn_readfirstlane(tid >> 6);
    int pstart = (s < 2) ? s * 4 : 8 + (s - 2) * 3;
    int pcnt   = (s < 2) ? 4 : 3;
    float o0 = 0.f, o1 = 0.f, o2 = 0.f, o3 = 0.f;
    for (int pp = 0; pp < 4; ++pp) {
        if (pp >= pcnt) break;
        int p = pstart + pp;
        int ci = (p >= 7) ? 1 : 0;
        int kd = p - ci * 7;
        const float* wrow = w + (ci * 343 + kd * 49);
#pragma unroll
        for (int kh = 0; kh < 7; ++kh) {
            const float* trow = &tile[ci][kd][h + kh][wg * 4];
            float4 r0 = *(const float4*)(trow);
            float4 r1 = *(const float4*)(trow + 4);
            float4 r2 = *(const float4*)(trow + 8);
            float rr[12] = {r0.x, r0.y, r0.z, r0.w, r1.x, r1.y, r1.z, r1.w,
                            r2.x, r2.y, r2.z, r2.w};
#pragma unroll
            for (int kw = 0; kw < 7; ++kw) {
                float wv = wrow[kh * 7 + kw];
                o0 += rr[kw + 0] * wv;
                o1 += rr[kw + 1] * wv;
                o2 += rr[kw + 2] * wv;
                o3 += rr[kw + 3] * wv;
            }
        }
    }
    int q = h * 16 + wg * 4;
    red[s][q + 0] = o0; red[s][q + 1] = o1; red[s][q + 2] = o2; red[s][q + 3] = o3;
    __syncthreads();
    float acc = red[0][tid] + red[1][tid] + red[2][tid] + red[3][tid];
    float sg = 1.0f / (1.0f + expf(-acc));
    scores[(size_t)b * NTOK + d * 256 + tid] = sg;
}

// ---------------- 4. qkv MFMA GEMM (+fused channel mean/max on j0==0 blocks) ----
// grid (12 j, 64 n, B), j fastest (A-tile L2 reuse).
// j<256 (q): qh[b*32+h][n][8] f16 PRE-SCALED by 8^-0.5*log2e.
// j>=256 (k,v): khv[b][n][j-256] f16 (k cols 0-255, v cols 256-511).
// j>=512 (v): additionally vt[b][c][n] fp32 for the dwconv residual.
__global__ __launch_bounds__(256)
void gemm_qkv(const float* __restrict__ A_, const float* __restrict__ W,
              _Float16* __restrict__ khv, float* __restrict__ vt,
              _Float16* __restrict__ qh, float* __restrict__ am) {
    __shared__ _Float16 Ws_h[64][72];
    __shared__ _Float16 Xs[64][72];
    __shared__ float ams[2][4][64];
    int b  = blockIdx.z;
    int j0 = blockIdx.x * 64;
    int n0 = blockIdx.y * 64;
    int t  = threadIdx.x;
    int lane = t & 63, wid = t >> 6;
    int wj = wid >> 1, wn = wid & 1;
    const float* A = A_ + (size_t)b * DIM * NTOK;
    bool do_am = (blockIdx.x == 0);

    f32x4 acc00 = {0.f,0.f,0.f,0.f}, acc01 = {0.f,0.f,0.f,0.f};
    f32x4 acc10 = {0.f,0.f,0.f,0.f}, acc11 = {0.f,0.f,0.f,0.f};
    float amsum = 0.f, ammax = -1e30f;

    for (int ks = 0; ks < 4; ++ks) {
        int c0 = ks * 64;
        if (ks) __syncthreads();
#pragma unroll
        for (int r = 0; r < 4; ++r) {
            int j  = r * 16 + (t >> 4);
            int cq = (t & 15) * 4;
            float4 wv = *(const float4*)(W + (size_t)(j0 + j) * DIM + c0 + cq);
            union { h16x2 h2[2]; uint2 u2; } p;
            p.h2[0] = __builtin_amdgcn_cvt_pkrtz(wv.x, wv.y);
            p.h2[1] = __builtin_amdgcn_cvt_pkrtz(wv.z, wv.w);
            *(auint2*)&Ws_h[j][cq] = p.u2;
        }
        {
            int nl = t & 63, cb = (t >> 6) * 16;
            float v[16];
#pragma unroll
            for (int i = 0; i < 16; ++i)
                v[i] = A[(size_t)(c0 + cb + i) * NTOK + n0 + nl];
            if (do_am) {
#pragma unroll
                for (int i = 0; i < 16; ++i) {
                    amsum += v[i]; ammax = fmaxf(ammax, v[i]);
                }
            }
            union { h16x2 h2[8]; int4 i4[2]; } u;
#pragma unroll
            for (int m = 0; m < 8; ++m)
                u.h2[m] = __builtin_amdgcn_cvt_pkrtz(v[2 * m], v[2 * m + 1]);
            *(aint4*)&Xs[nl][cb]     = u.i4[0];
            *(aint4*)&Xs[nl][cb + 8] = u.i4[1];
        }
        __syncthreads();
        const _Float16* wA = &Ws_h[wj * 32 + (lane & 15)][(lane >> 4) * 8];
        const _Float16* xB = &Xs [wn * 32 + (lane & 15)][(lane >> 4) * 8];
#pragma unroll
        for (int s = 0; s < 2; ++s) {
            f16x8 a0  = *(const f16x8a*)(wA + s * 32);
            f16x8 a1  = *(const f16x8a*)(wA + 16 * 72 + s * 32);
            f16x8 b0v = *(const f16x8a*)(xB + s * 32);
            f16x8 b1v = *(const f16x8a*)(xB + 16 * 72 + s * 32);
            acc00 = __builtin_amdgcn_mfma_f32_16x16x32_f16(a0, b0v, acc00, 0, 0, 0);
            acc01 = __builtin_amdgcn_mfma_f32_16x16x32_f16(a0, b1v, acc01, 0, 0, 0);
            acc10 = __builtin_amdgcn_mfma_f32_16x16x32_f16(a1, b0v, acc10, 0, 0, 0);
            acc11 = __builtin_amdgcn_mfma_f32_16x16x32_f16(a1, b1v, acc11, 0, 0, 0);
        }
    }

    if (do_am) {
        int nl = t & 63, cbg = t >> 6;
        ams[0][cbg][nl] = amsum;
        ams[1][cbg][nl] = ammax;
        __syncthreads();
        if (t < 64) {
            float ss = (ams[0][0][t] + ams[0][1][t]) + (ams[0][2][t] + ams[0][3][t]);
            float mm = fmaxf(fmaxf(ams[1][0][t], ams[1][1][t]),
                             fmaxf(ams[1][2][t], ams[1][3][t]));
            am[(size_t)b * 2 * NTOK + n0 + t]        = ss * (1.0f / DIM);
            am[(size_t)b * 2 * NTOK + NTOK + n0 + t] = mm;
        }
    }

    const float qsc = 0.35355339059327373f * 1.4426950408889634f;
    int jb0 = j0 + wj * 32 + (lane >> 4) * 4;
    int nn0 = n0 + wn * 32 + (lane & 15);
#pragma unroll
    for (int jt = 0; jt < 2; ++jt) {
#pragma unroll
        for (int nt = 0; nt < 2; ++nt) {
            f32x4 ac = (jt == 0) ? (nt == 0 ? acc00 : acc01)
                                 : (nt == 0 ? acc10 : acc11);
            int jb = jb0 + jt * 16;
            int n  = nn0 + nt * 16;
            if (jb < 256) {
                int hh = jb >> 3, dq = jb & 7;
                union { h16x2 h2[2]; uint2 u2; } p;
                p.h2[0] = __builtin_amdgcn_cvt_pkrtz(ac[0] * qsc, ac[1] * qsc);
                p.h2[1] = __builtin_amdgcn_cvt_pkrtz(ac[2] * qsc, ac[3] * qsc);
                *(auint2*)(qh + ((size_t)((b << 5) | hh) * NTOK + n) * 8 + dq) = p.u2;
            } else {
                union { h16x2 h2[2]; uint2 u2; } p;
                p.h2[0] = __builtin_amdgcn_cvt_pkrtz(ac[0], ac[1]);
                p.h2[1] = __builtin_amdgcn_cvt_pkrtz(ac[2], ac[3]);
                *(auint2*)(khv + ((size_t)b * NTOK + n) * 512 + (jb - 256)) = p.u2;
                if (jb >= 512) {
                    float* vp = vt + (size_t)(b * DIM + jb - 512) * NTOK + n;
                    vp[0] = ac[0]; vp[NTOK] = ac[1];
                    vp[2 * NTOK] = ac[2]; vp[3 * NTOK] = ac[3];
                }
            }
        }
    }
}

// ---------------- 3+4b. fused top-512 radix-select + K/V gather per (b,h) -------
// Each block redundantly radix-selects (order-free set; ties -> lowest index),
// then gathers its head's K/V 16B granules from khv into packed kvs.
__global__ __launch_bounds__(256)
void kv_topk(const float* __restrict__ scores, const _Float16* __restrict__ khv,
             _Float16* __restrict__ kvs) {
    __shared__ int wsum[4];
    __shared__ unsigned int s_thr;
    __shared__ int s_cnt;
    __shared__ unsigned int tiem[NTOK / 32];
    __shared__ int tiep[NTOK / 32];
    __shared__ int sel[KTOP];
    int bh = blockIdx.x;           // b*32 + h
    int h = bh & 31, b = bh >> 5;
    int tid = threadIdx.x, lane = tid & 63, wid = tid >> 6;
    unsigned int v[16];
#pragma unroll
    for (int j = 0; j < 16; ++j)
        v[j] = __float_as_uint(scores[b * NTOK + j * 256 + tid]);  // positive, <1.0
    if (tid == 0) { s_thr = 0u; s_cnt = 0; }
    if (tid < NTOK / 32) tiem[tid] = 0u;
    __syncthreads();
    for (int bit = 29; bit >= 0; --bit) {
        unsigned int test = s_thr | (1u << bit);
        int c = 0;
#pragma unroll
        for (int j = 0; j < 16; ++j)
            c += (int)__popcll(__ballot(v[j] >= test));
        if (lane == 0) wsum[wid] = c;
        __syncthreads();
        if (tid == 0) {
            int tot = wsum[0] + wsum[1] + wsum[2] + wsum[3];
            if (tot >= KTOP) s_thr = test;
        }
        __syncthreads();
    }
    unsigned int T = s_thr;
    {
        int c = 0;
#pragma unroll
        for (int j = 0; j < 16; ++j)
            c += (int)__popcll(__ballot(v[j] > T));
        if (lane == 0) wsum[wid] = c;
    }
    __syncthreads();
    int cnt_gt = wsum[0] + wsum[1] + wsum[2] + wsum[3];
    int krem = KTOP - cnt_gt;
#pragma unroll
    for (int j = 0; j < 16; ++j) {
        int i = j * 256 + tid;
        if (v[j] > T) sel[atomicAdd(&s_cnt, 1)] = i;
        if (v[j] == T) atomicOr(&tiem[i >> 5], 1u << (i & 31));
    }
    __syncthreads();
    if (tid == 0) {
        int c = 0;
        for (int w2 = 0; w2 < NTOK / 32; ++w2) { tiep[w2] = c; c += __popc(tiem[w2]); }
    }
    __syncthreads();
#pragma unroll
    for (int j = 0; j < 16; ++j) {
        int i = j * 256 + tid;
        if (v[j] == T) {
            int r = tiep[i >> 5] + __popc(tiem[i >> 5] & ((1u << (i & 31)) - 1u));
            if (r < krem) sel[cnt_gt + r] = i;
        }
    }
    __syncthreads();
    aint4* dst = (aint4*)(kvs + (size_t)bh * KTOP * 16);
    const _Float16* src = khv + (size_t)b * NTOK * 512;
    for (int i = tid; i < KTOP; i += 256) {
        int tok = sel[i];
        aint4 k16 = *(const aint4*)(src + (size_t)tok * 512 + h * 8);
        aint4 v16 = *(const aint4*)(src + (size_t)tok * 512 + 256 + h * 8);
        dst[2 * i]     = k16;
        dst[2 * i + 1] = v16;
    }
}

// ---------------- 5. attention via MFMA (f16 frags, fp32 acc, ones-row lsum) ----
__global__ __launch_bounds__(256)
void attn_mfma(const _Float16* __restrict__ qh, const _Float16* __restrict__ kvs,
               float* __restrict__ at) {
    __shared__ _Float16 Klds[KTOP][8];        // [k][d] 16B rows
    __shared__ _Float16 Vt[9][KTOP + 8];      // [d][k]; row 8 = ones (lsum trick)
    __shared__ _Float16 Plds[4][16 * 40];     // per-wave [q][40]
    int blk = blockIdx.x;                     // ((b*32+h)*16 + tb)
    int tb = blk & 15, bh = blk >> 4;
    int tid = threadIdx.x, lane = tid & 63, wid = tid >> 6;

    // ---- linear load of staged K/V -> LDS (+ones row) ----
    const aint4* kvb = (const aint4*)(kvs + (size_t)bh * KTOP * 16);
    for (int i = tid; i < KTOP; i += 256) {
        int4 kk = kvb[2 * i];
        int4 vv = kvb[2 * i + 1];
        *(aint4*)&Klds[i][0] = kk;
        union { int4 i4; unsigned short u[8]; } uv; uv.i4 = vv;
        unsigned short* vcol = (unsigned short*)&Vt[0][0];
#pragma unroll
        for (int d = 0; d < 8; ++d)
            vcol[d * (KTOP + 8) + i] = uv.u[d];
        vcol[8 * (KTOP + 8) + i] = 0x3C00;    // f16 1.0
    }

    // ---- Q fragments: direct f16 load (pre-scaled in gemm_qkv) ----
    int qblk = tb * 256 + wid * 64;
    int qcol = lane & 15;
    const _Float16* qb = qh + (size_t)bh * NTOK * 8;
    f16x8 qf[4];
#pragma unroll
    for (int t = 0; t < 4; ++t)
        qf[t] = *(const f16x8a*)(qb + (size_t)(qblk + t * 16 + qcol) * 8);
    __syncthreads();

    int g = lane >> 4;
    _Float16* pw = &Plds[wid][(lane & 15) * 40 + g * 4];
    const f16x8a* pr = (const f16x8a*)&Plds[wid][(lane & 15) * 40 + g * 8];
    int vr15 = lane & 15; if (vr15 > 8) vr15 = 8;
    const _Float16* vrow = &Vt[vr15][g * 8];

    f32x4 acc[4];
#pragma unroll
    for (int t = 0; t < 4; ++t) acc[t] = (f32x4){0.f, 0.f, 0.f, 0.f};
    const f32x4 z = {0.f, 0.f, 0.f, 0.f};

    for (int ks = 0; ks < 16; ++ks) {
        f16x8 ka = {}, kb = {};
        if (lane < 16) {
            ka = *(const f16x8a*)&Klds[ks * 32 + lane][0];
            kb = *(const f16x8a*)&Klds[ks * 32 + 16 + lane][0];
        }
        f16x8 vf = *(const f16x8a*)&vrow[ks * 32];
#pragma unroll
        for (int t = 0; t < 4; ++t) {
            f32x4 c0 = __builtin_amdgcn_mfma_f32_16x16x32_f16(ka, qf[t], z, 0, 0, 0);
            f32x4 c1 = __builtin_amdgcn_mfma_f32_16x16x32_f16(kb, qf[t], z, 0, 0, 0);
            float p0 = __builtin_amdgcn_exp2f(c0[0]);
            float p1 = __builtin_amdgcn_exp2f(c0[1]);
            float p2 = __builtin_amdgcn_exp2f(c0[2]);
            float p3 = __builtin_amdgcn_exp2f(c0[3]);
            float p4 = __builtin_amdgcn_exp2f(c1[0]);
            float p5 = __builtin_amdgcn_exp2f(c1[1]);
            float p6 = __builtin_amdgcn_exp2f(c1[2]);
            float p7 = __builtin_amdgcn_exp2f(c1[3]);
            union { h16x2 h2[2]; uint2 u2; } w01, w23;
            w01.h2[0] = __builtin_amdgcn_cvt_pkrtz(p0, p1);
            w01.h2[1] = __builtin_amdgcn_cvt_pkrtz(p2, p3);
            w23.h2[0] = __builtin_amdgcn_cvt_pkrtz(p4, p5);
            w23.h2[1] = __builtin_amdgcn_cvt_pkrtz(p6, p7);
            *(auint2*)pw        = w01.u2;     // tile0 rows g*4..+3
            *(auint2*)(pw + 16) = w23.u2;     // tile1 rows 16+g*4..+3
            f16x8 pf = *pr;                   // B-frag: rows g*8..+7, col q
            acc[t] = __builtin_amdgcn_mfma_f32_16x16x32_f16(vf, pf, acc[t], 0, 0, 0);
        }
    }

    // ---- epilogue: C row 8 = sum(p); broadcast, normalize, write (c-major) ----
    int b = bh >> 5, h = bh & 31;
#pragma unroll
    for (int t = 0; t < 4; ++t) {
        float ls = __shfl(acc[t][0], 32 + (lane & 15));
        float inv = 1.0f / ls;
        if (lane < 32) {
            int n = qblk + t * 16 + (lane & 15);
            int dbase = (lane >> 4) * 4;
            float* op = at + ((size_t)(b * DIM + h * HDIM + dbase)) * NTOK + n;
            op[0]        = acc[t][0] * inv;
            op[NTOK]     = acc[t][1] * inv;
            op[2 * NTOK] = acc[t][2] * inv;
            op[3 * NTOK] = acc[t][3] * inv;
        }
    }
}

// ---------------- 7. depthwise 3x3x3 conv ----------------
__global__ __launch_bounds__(256)
void dw_conv(const float* __restrict__ vt, const float* __restrict__ dww,
             const float* __restrict__ dwb, float* __restrict__ out) {
    __shared__ float tile[NTOK];     // 16 KB, one (b,c) volume
    int bc = blockIdx.x;             // b*DIM + c
    int b = bc / DIM, c = bc % DIM;
    int tid = threadIdx.x;
    const float* src = vt + (size_t)(b * DIM + c) * NTOK;
    for (int i = tid; i < NTOK; i += 256) tile[i] = src[i];
    float wreg[27];
#pragma unroll
    for (int i = 0; i < 27; ++i) wreg[i] = dww[c * 27 + i];
    float bias = dwb[c];
    __syncthreads();
    for (int i = tid; i < NTOK; i += 256) {
        int d = i >> 8, h = (i >> 4) & 15, w = i & 15;
        float acc = bias;
#pragma unroll
        for (int kd = 0; kd < 3; ++kd) {
            int dz = d + kd - 1; if (dz < 0 || dz > 15) continue;
#pragma unroll
            for (int kh = 0; kh < 3; ++kh) {
                int hz = h + kh - 1; if (hz < 0 || hz > 15) continue;
#pragma unroll
                for (int kw = 0; kw < 3; ++kw) {
                    int wz = w + kw - 1; if (wz < 0 || wz > 15) continue;
                    acc += tile[(dz * 16 + hz) * 16 + wz] * wreg[(kd * 3 + kh) * 3 + kw];
                }
            }
        }
        out[(size_t)(b * DIM + c) * NTOK + i] = acc;
    }
}

// ---------------- 6+8. fused proj + pw GEMM: out = proj(at)+pw(dw)+biases ------
__global__ __launch_bounds__(256)
void gemm_dual(const float* __restrict__ At, const float* __restrict__ Dw,
               const float* __restrict__ Wp_, const float* __restrict__ Wq_,
               const float* __restrict__ bp_, const float* __restrict__ bq_,
               float* __restrict__ outbase) {
    __shared__ _Float16 Wp[64][72];
    __shared__ _Float16 Wq[64][72];
    __shared__ _Float16 Xa[64][72];
    __shared__ _Float16 Xd[64][72];
    int b  = blockIdx.z;
    int j0 = blockIdx.x * 64;
    int n0 = blockIdx.y * 64;
    int t  = threadIdx.x;
    int lane = t & 63, wid = t >> 6;
    int wj = wid >> 1, wn = wid & 1;
    const float* Aa = At + (size_t)b * DIM * NTOK;
    const float* Ad = Dw + (size_t)b * DIM * NTOK;

    f32x4 acc00 = {0.f,0.f,0.f,0.f}, acc01 = {0.f,0.f,0.f,0.f};
    f32x4 acc10 = {0.f,0.f,0.f,0.f}, acc11 = {0.f,0.f,0.f,0.f};

    for (int ks = 0; ks < 4; ++ks) {
        int c0 = ks * 64;
        if (ks) __syncthreads();
#pragma unroll
        for (int r = 0; r < 4; ++r) {
            int j  = r * 16 + (t >> 4);
            int cq = (t & 15) * 4;
            float4 wv = *(const float4*)(Wp_ + (size_t)(j0 + j) * DIM + c0 + cq);
            float4 wu = *(const float4*)(Wq_ + (size_t)(j0 + j) * DIM + c0 + cq);
            union { h16x2 h2[2]; uint2 u2; } p, q;
            p.h2[0] = __builtin_amdgcn_cvt_pkrtz(wv.x, wv.y);
            p.h2[1] = __builtin_amdgcn_cvt_pkrtz(wv.z, wv.w);
            q.h2[0] = __builtin_amdgcn_cvt_pkrtz(wu.x, wu.y);
            q.h2[1] = __builtin_amdgcn_cvt_pkrtz(wu.z, wu.w);
            *(auint2*)&Wp[j][cq] = p.u2;
            *(auint2*)&Wq[j][cq] = q.u2;
        }
        {
            int nl = t & 63, cb = (t >> 6) * 16;
            float v[16];
#pragma unroll
            for (int i = 0; i < 16; ++i)
                v[i] = Aa[(size_t)(c0 + cb + i) * NTOK + n0 + nl];
            union { h16x2 h2[8]; int4 i4[2]; } u;
#pragma unroll
            for (int m = 0; m < 8; ++m)
                u.h2[m] = __builtin_amdgcn_cvt_pkrtz(v[2 * m], v[2 * m + 1]);
            *(aint4*)&Xa[nl][cb]     = u.i4[0];
            *(aint4*)&Xa[nl][cb + 8] = u.i4[1];
#pragma unroll
            for (int i = 0; i < 16; ++i)
                v[i] = Ad[(size_t)(c0 + cb + i) * NTOK + n0 + nl];
#pragma unroll
            for (int m = 0; m < 8; ++m)
                u.h2[m] = __builtin_amdgcn_cvt_pkrtz(v[2 * m], v[2 * m + 1]);
            *(aint4*)&Xd[nl][cb]     = u.i4[0];
            *(aint4*)&Xd[nl][cb + 8] = u.i4[1];
        }
        __syncthreads();
        const _Float16* wPa = &Wp[wj * 32 + (lane & 15)][(lane >> 4) * 8];
        const _Float16* wQa = &Wq[wj * 32 + (lane & 15)][(lane >> 4) * 8];
        const _Float16* xAa = &Xa[wn * 32 + (lane & 15)][(lane >> 4) * 8];
        const _Float16* xDa = &Xd[wn * 32 + (lane & 15)][(lane >> 4) * 8];
#pragma unroll
        for (int s = 0; s < 2; ++s) {
            f16x8 p0 = *(const f16x8a*)(wPa + s * 32);
            f16x8 p1 = *(const f16x8a*)(wPa + 16 * 72 + s * 32);
            f16x8 q0 = *(const f16x8a*)(wQa + s * 32);
            f16x8 q1 = *(const f16x8a*)(wQa + 16 * 72 + s * 32);
            f16x8 a0 = *(const f16x8a*)(xAa + s * 32);
            f16x8 a1 = *(const f16x8a*)(xAa + 16 * 72 + s * 32);
            f16x8 d0 = *(const f16x8a*)(xDa + s * 32);
            f16x8 d1 = *(const f16x8a*)(xDa + 16 * 72 + s * 32);
            acc00 = __builtin_amdgcn_mfma_f32_16x16x32_f16(p0, a0, acc00, 0, 0, 0);
            acc00 = __builtin_amdgcn_mfma_f32_16x16x32_f16(q0, d0, acc00, 0, 0, 0);
            acc01 = __builtin_amdgcn_mfma_f32_16x16x32_f16(p0, a1, acc01, 0, 0, 0);
            acc01 = __builtin_amdgcn_mfma_f32_16x16x32_f16(q0, d1, acc01, 0, 0, 0);
            acc10 = __builtin_amdgcn_mfma_f32_16x16x32_f16(p1, a0, acc10, 0, 0, 0);
            acc10 = __builtin_amdgcn_mfma_f32_16x16x32_f16(q1, d0, acc10, 0, 0, 0);
            acc11 = __builtin_amdgcn_mfma_f32_16x16x32_f16(p1, a1, acc11, 0, 0, 0);
            acc11 = __builtin_amdgcn_mfma_f32_16x16x32_f16(q1, d1, acc11, 0, 0, 0);
        }
    }

    int jb0 = j0 + wj * 32 + (lane >> 4) * 4;
    int nn0 = n0 + wn * 32 + (lane & 15);
#pragma unroll
    for (int jt = 0; jt < 2; ++jt) {
#pragma unroll
        for (int nt = 0; nt < 2; ++nt) {
            f32x4 ac = (jt == 0) ? (nt == 0 ? acc00 : acc01)
                                 : (nt == 0 ? acc10 : acc11);
            int jb = jb0 + jt * 16;
            int n  = nn0 + nt * 16;
            float4 bp = *(const float4*)(bp_ + jb);
            float4 bq = *(const float4*)(bq_ + jb);
            float* op = outbase + (size_t)(b * DIM + jb) * NTOK + n;
            op[0]        = ac[0] + bp.x + bq.x;
            op[NTOK]     = ac[1] + bp.y + bq.y;
            op[2 * NTOK] = ac[2] + bp.z + bq.z;
            op[3 * NTOK] = ac[3] + bp.w + bq.w;
        }
    }
}

extern "C" void kernel_launch(void* const* d_in, const int* in_sizes, int n_in,
                              void* d_out, int out_size, void* d_ws, size_t ws_size,
                              hipStream_t stream) {
    const float* x      = (const float*)d_in[0];
    const float* spa_w  = (const float*)d_in[1];
    const float* qkv_w  = (const float*)d_in[2];
    const float* proj_w = (const float*)d_in[3];
    const float* proj_b = (const float*)d_in[4];
    const float* dw_w   = (const float*)d_in[5];
    const float* dw_b   = (const float*)d_in[6];
    const float* pw_w   = (const float*)d_in[7];
    const float* pw_b   = (const float*)d_in[8];
    float* out = (float*)d_out;
    float* ws  = (float*)d_ws;

    float* am     = ws + AM_OFF;
    float* scores = ws + SC_OFF;
    float* vtbuf  = ws + VT_OFF;
    float* atbuf  = ws + AT_OFF;
    float* dwbuf  = ws + DW_OFF;
    _Float16* kvs = (_Float16*)(ws + KVS_OFF);
    _Float16* khv = (_Float16*)(ws + KHV_OFF);
    _Float16* qh  = (_Float16*)(ws + QH_OFF);

    gemm_qkv<<<dim3(12, 64, NB), 256, 0, stream>>>(x, qkv_w, khv, vtbuf, qh, am);
    spa_conv<<<NB * 16, 256, 0, stream>>>(am, spa_w, scores);
    kv_topk<<<NB * NHEAD, 256, 0, stream>>>(scores, khv, kvs);
    dw_conv<<<NB * DIM, 256, 0, stream>>>(vtbuf, dw_w, dw_b, dwbuf);
    attn_mfma<<<NB * NHEAD * 16, 256, 0, stream>>>(qh, kvs, atbuf);
    gemm_dual<<<dim3(4, 64, NB), 256, 0, stream>>>(atbuf, dwbuf, proj_w, pw_w,
                                                   proj_b, pw_b, out);
}

// Round 10
// 89.139 us; speedup vs baseline: 1.3364x; 1.2284x over previous
//
#include <hip/hip_runtime.h>
#include <math.h>

#define DIM    256
#define NHEAD  32
#define HDIM   8
#define KTOP   512
#define NTOK   4096   // 16*16*16
#define NB     2

typedef float    f32x4  __attribute__((ext_vector_type(4)));
typedef _Float16 f16x8  __attribute__((ext_vector_type(8)));
typedef __fp16   h16x2  __attribute__((ext_vector_type(2)));   // cvt_pkrtz return type
typedef f16x8 f16x8a __attribute__((may_alias));
typedef int4  aint4  __attribute__((may_alias));
typedef uint2 auint2 __attribute__((may_alias));

// ---------------- workspace layout (float offsets) ----------------
#define AM_OFF   0                         // [B][2][NTOK] avg/max fp32
#define SC_OFF   16384                     // [B][NTOK] scores fp32
#define VT_OFF   24576                     // [B][DIM][NTOK] f16 v c-major
#define AT_OFF   (VT_OFF + 1048576)        // [B][DIM][NTOK] f16 attn out
#define DW_OFF   (AT_OFF + 1048576)        // [B][DIM][NTOK] f16 dwconv out
#define KVS_OFF  (DW_OFF + 1048576)        // [B*32][512][16] f16 gathered K/V
#define KHV_OFF  (KVS_OFF + 131072)        // [B][NTOK][512] f16 (k:0-255, v:256-511)
#define QH_OFF   (KHV_OFF + 2097152)       // [B*32][NTOK][8] f16 q pre-scaled

// ---------------- 2. 7x7x7 conv (2->1 ch) + sigmoid, LDS-staged ----------------
__global__ __launch_bounds__(256)
void spa_conv(const float* __restrict__ am, const float* __restrict__ w,
              float* __restrict__ scores) {
    __shared__ float tile[2][7][22][24];   // 28.9 KB
    __shared__ float red[4][256];
    int bd = blockIdx.x;          // b*16 + d
    int b = bd >> 4, d = bd & 15;
    int tid = threadIdx.x;
    float4* t4 = (float4*)&tile[0][0][0][0];
    for (int i = tid; i < (2 * 7 * 22 * 24) / 4; i += 256)
        t4[i] = (float4){0.f, 0.f, 0.f, 0.f};
    __syncthreads();
    for (int it = 0; it < 14; ++it) {
        int j = it * 256 + tid;
        int ci = (j >= 1792) ? 1 : 0;
        int r = j - ci * 1792;
        int kd = r >> 8, pos = r & 255;
        int dz = d + kd - 3;
        if ((unsigned)dz < 16u)
            tile[ci][kd][(pos >> 4) + 3][(pos & 15) + 3] =
                am[((size_t)b * 2 + ci) * NTOK + dz * 256 + pos];
    }
    __syncthreads();
    int h  = (tid >> 2) & 15;
    int wg = tid & 3;
    int s  = __builtin_amdgcn_readfirstlane(tid >> 6);
    int pstart = (s < 2) ? s * 4 : 8 + (s - 2) * 3;
    int pcnt   = (s < 2) ? 4 : 3;
    float o0 = 0.f, o1 = 0.f, o2 = 0.f, o3 = 0.f;
    for (int pp = 0; pp < 4; ++pp) {
        if (pp >= pcnt) break;
        int p = pstart + pp;
        int ci = (p >= 7) ? 1 : 0;
        int kd = p - ci * 7;
        const float* wrow = w + (ci * 343 + kd * 49);
#pragma unroll
        for (int kh = 0; kh < 7; ++kh) {
            const float* trow = &tile[ci][kd][h + kh][wg * 4];
            float4 r0 = *(const float4*)(trow);
            float4 r1 = *(const float4*)(trow + 4);
            float4 r2 = *(const float4*)(trow + 8);
            float rr[12] = {r0.x, r0.y, r0.z, r0.w, r1.x, r1.y, r1.z, r1.w,
                            r2.x, r2.y, r2.z, r2.w};
#pragma unroll
            for (int kw = 0; kw < 7; ++kw) {
                float wv = wrow[kh * 7 + kw];
                o0 += rr[kw + 0] * wv;
                o1 += rr[kw + 1] * wv;
                o2 += rr[kw + 2] * wv;
                o3 += rr[kw + 3] * wv;
            }
        }
    }
    int q = h * 16 + wg * 4;
    red[s][q + 0] = o0; red[s][q + 1] = o1; red[s][q + 2] = o2; red[s][q + 3] = o3;
    __syncthreads();
    float acc = red[0][tid] + red[1][tid] + red[2][tid] + red[3][tid];
    float sg = 1.0f / (1.0f + expf(-acc));
    scores[(size_t)b * NTOK + d * 256 + tid] = sg;
}

// ---------------- 4. qkv MFMA GEMM (+fused channel mean/max on j0==0 blocks) ----
// grid (12 j, 64 n, B), j fastest (A-tile L2 reuse).
// j<256 (q): qh[b*32+h][n][8] f16 PRE-SCALED by 8^-0.5*log2e.
// j>=256 (k,v): khv[b][n][j-256] f16 (k cols 0-255, v cols 256-511).
// j>=512 (v): additionally vt[b][c][n] f16 for the dwconv residual.
__global__ __launch_bounds__(256)
void gemm_qkv(const float* __restrict__ A_, const float* __restrict__ W,
              _Float16* __restrict__ khv, _Float16* __restrict__ vt,
              _Float16* __restrict__ qh, float* __restrict__ am) {
    __shared__ _Float16 Ws_h[64][72];
    __shared__ _Float16 Xs[64][72];
    __shared__ float ams[2][4][64];
    int b  = blockIdx.z;
    int j0 = blockIdx.x * 64;
    int n0 = blockIdx.y * 64;
    int t  = threadIdx.x;
    int lane = t & 63, wid = t >> 6;
    int wj = wid >> 1, wn = wid & 1;
    const float* A = A_ + (size_t)b * DIM * NTOK;
    bool do_am = (blockIdx.x == 0);

    f32x4 acc00 = {0.f,0.f,0.f,0.f}, acc01 = {0.f,0.f,0.f,0.f};
    f32x4 acc10 = {0.f,0.f,0.f,0.f}, acc11 = {0.f,0.f,0.f,0.f};
    float amsum = 0.f, ammax = -1e30f;

    for (int ks = 0; ks < 4; ++ks) {
        int c0 = ks * 64;
        if (ks) __syncthreads();
#pragma unroll
        for (int r = 0; r < 4; ++r) {
            int j  = r * 16 + (t >> 4);
            int cq = (t & 15) * 4;
            float4 wv = *(const float4*)(W + (size_t)(j0 + j) * DIM + c0 + cq);
            union { h16x2 h2[2]; uint2 u2; } p;
            p.h2[0] = __builtin_amdgcn_cvt_pkrtz(wv.x, wv.y);
            p.h2[1] = __builtin_amdgcn_cvt_pkrtz(wv.z, wv.w);
            *(auint2*)&Ws_h[j][cq] = p.u2;
        }
        {
            int nl = t & 63, cb = (t >> 6) * 16;
            float v[16];
#pragma unroll
            for (int i = 0; i < 16; ++i)
                v[i] = A[(size_t)(c0 + cb + i) * NTOK + n0 + nl];
            if (do_am) {
#pragma unroll
                for (int i = 0; i < 16; ++i) {
                    amsum += v[i]; ammax = fmaxf(ammax, v[i]);
                }
            }
            union { h16x2 h2[8]; int4 i4[2]; } u;
#pragma unroll
            for (int m = 0; m < 8; ++m)
                u.h2[m] = __builtin_amdgcn_cvt_pkrtz(v[2 * m], v[2 * m + 1]);
            *(aint4*)&Xs[nl][cb]     = u.i4[0];
            *(aint4*)&Xs[nl][cb + 8] = u.i4[1];
        }
        __syncthreads();
        const _Float16* wA = &Ws_h[wj * 32 + (lane & 15)][(lane >> 4) * 8];
        const _Float16* xB = &Xs [wn * 32 + (lane & 15)][(lane >> 4) * 8];
#pragma unroll
        for (int s = 0; s < 2; ++s) {
            f16x8 a0  = *(const f16x8a*)(wA + s * 32);
            f16x8 a1  = *(const f16x8a*)(wA + 16 * 72 + s * 32);
            f16x8 b0v = *(const f16x8a*)(xB + s * 32);
            f16x8 b1v = *(const f16x8a*)(xB + 16 * 72 + s * 32);
            acc00 = __builtin_amdgcn_mfma_f32_16x16x32_f16(a0, b0v, acc00, 0, 0, 0);
            acc01 = __builtin_amdgcn_mfma_f32_16x16x32_f16(a0, b1v, acc01, 0, 0, 0);
            acc10 = __builtin_amdgcn_mfma_f32_16x16x32_f16(a1, b0v, acc10, 0, 0, 0);
            acc11 = __builtin_amdgcn_mfma_f32_16x16x32_f16(a1, b1v, acc11, 0, 0, 0);
        }
    }

    if (do_am) {
        int nl = t & 63, cbg = t >> 6;
        ams[0][cbg][nl] = amsum;
        ams[1][cbg][nl] = ammax;
        __syncthreads();
        if (t < 64) {
            float ss = (ams[0][0][t] + ams[0][1][t]) + (ams[0][2][t] + ams[0][3][t]);
            float mm = fmaxf(fmaxf(ams[1][0][t], ams[1][1][t]),
                             fmaxf(ams[1][2][t], ams[1][3][t]));
            am[(size_t)b * 2 * NTOK + n0 + t]        = ss * (1.0f / DIM);
            am[(size_t)b * 2 * NTOK + NTOK + n0 + t] = mm;
        }
    }

    const float qsc = 0.35355339059327373f * 1.4426950408889634f;
    int jb0 = j0 + wj * 32 + (lane >> 4) * 4;
    int nn0 = n0 + wn * 32 + (lane & 15);
#pragma unroll
    for (int jt = 0; jt < 2; ++jt) {
#pragma unroll
        for (int nt = 0; nt < 2; ++nt) {
            f32x4 ac = (jt == 0) ? (nt == 0 ? acc00 : acc01)
                                 : (nt == 0 ? acc10 : acc11);
            int jb = jb0 + jt * 16;
            int n  = nn0 + nt * 16;
            if (jb < 256) {
                int hh = jb >> 3, dq = jb & 7;
                union { h16x2 h2[2]; uint2 u2; } p;
                p.h2[0] = __builtin_amdgcn_cvt_pkrtz(ac[0] * qsc, ac[1] * qsc);
                p.h2[1] = __builtin_amdgcn_cvt_pkrtz(ac[2] * qsc, ac[3] * qsc);
                *(auint2*)(qh + ((size_t)((b << 5) | hh) * NTOK + n) * 8 + dq) = p.u2;
            } else {
                union { h16x2 h2[2]; uint2 u2; } p;
                p.h2[0] = __builtin_amdgcn_cvt_pkrtz(ac[0], ac[1]);
                p.h2[1] = __builtin_amdgcn_cvt_pkrtz(ac[2], ac[3]);
                *(auint2*)(khv + ((size_t)b * NTOK + n) * 512 + (jb - 256)) = p.u2;
                if (jb >= 512) {
                    _Float16* vp = vt + (size_t)(b * DIM + jb - 512) * NTOK + n;
                    vp[0]        = (_Float16)ac[0];
                    vp[NTOK]     = (_Float16)ac[1];
                    vp[2 * NTOK] = (_Float16)ac[2];
                    vp[3 * NTOK] = (_Float16)ac[3];
                }
            }
        }
    }
}

// ---------------- 3+4b. fused top-512 radix-select + K/V gather per (b,h) -------
__global__ __launch_bounds__(256)
void kv_topk(const float* __restrict__ scores, const _Float16* __restrict__ khv,
             _Float16* __restrict__ kvs) {
    __shared__ int wsum[4];
    __shared__ unsigned int s_thr;
    __shared__ int s_cnt;
    __shared__ unsigned int tiem[NTOK / 32];
    __shared__ int tiep[NTOK / 32];
    __shared__ int sel[KTOP];
    int bh = blockIdx.x;           // b*32 + h
    int h = bh & 31, b = bh >> 5;
    int tid = threadIdx.x, lane = tid & 63, wid = tid >> 6;
    unsigned int v[16];
#pragma unroll
    for (int j = 0; j < 16; ++j)
        v[j] = __float_as_uint(scores[b * NTOK + j * 256 + tid]);  // positive, <1.0
    if (tid == 0) { s_thr = 0u; s_cnt = 0; }
    if (tid < NTOK / 32) tiem[tid] = 0u;
    __syncthreads();
    for (int bit = 29; bit >= 0; --bit) {
        unsigned int test = s_thr | (1u << bit);
        int c = 0;
#pragma unroll
        for (int j = 0; j < 16; ++j)
            c += (int)__popcll(__ballot(v[j] >= test));
        if (lane == 0) wsum[wid] = c;
        __syncthreads();
        if (tid == 0) {
            int tot = wsum[0] + wsum[1] + wsum[2] + wsum[3];
            if (tot >= KTOP) s_thr = test;
        }
        __syncthreads();
    }
    unsigned int T = s_thr;
    {
        int c = 0;
#pragma unroll
        for (int j = 0; j < 16; ++j)
            c += (int)__popcll(__ballot(v[j] > T));
        if (lane == 0) wsum[wid] = c;
    }
    __syncthreads();
    int cnt_gt = wsum[0] + wsum[1] + wsum[2] + wsum[3];
    int krem = KTOP - cnt_gt;
#pragma unroll
    for (int j = 0; j < 16; ++j) {
        int i = j * 256 + tid;
        if (v[j] > T) sel[atomicAdd(&s_cnt, 1)] = i;
        if (v[j] == T) atomicOr(&tiem[i >> 5], 1u << (i & 31));
    }
    __syncthreads();
    if (tid == 0) {
        int c = 0;
        for (int w2 = 0; w2 < NTOK / 32; ++w2) { tiep[w2] = c; c += __popc(tiem[w2]); }
    }
    __syncthreads();
#pragma unroll
    for (int j = 0; j < 16; ++j) {
        int i = j * 256 + tid;
        if (v[j] == T) {
            int r = tiep[i >> 5] + __popc(tiem[i >> 5] & ((1u << (i & 31)) - 1u));
            if (r < krem) sel[cnt_gt + r] = i;
        }
    }
    __syncthreads();
    aint4* dst = (aint4*)(kvs + (size_t)bh * KTOP * 16);
    const _Float16* src = khv + (size_t)b * NTOK * 512;
    for (int i = tid; i < KTOP; i += 256) {
        int tok = sel[i];
        aint4 k16 = *(const aint4*)(src + (size_t)tok * 512 + h * 8);
        aint4 v16 = *(const aint4*)(src + (size_t)tok * 512 + 256 + h * 8);
        dst[2 * i]     = k16;
        dst[2 * i + 1] = v16;
    }
}

// ---------------- 5+7. fused attention + depthwise conv (independent works) -----
struct AttnSm {
    _Float16 Klds[KTOP][8];        // [k][d] 16B rows
    _Float16 Vt[9][KTOP + 8];      // [d][k]; row 8 = ones (lsum trick)
    _Float16 Plds[4][16 * 40];     // per-wave [q][40]
};
union FusedSm { AttnSm a; float dwtile[NTOK]; };

__global__ __launch_bounds__(256)
void attn_dw(const _Float16* __restrict__ qh, const _Float16* __restrict__ kvs,
             _Float16* __restrict__ at,
             const _Float16* __restrict__ vt, const float* __restrict__ dww,
             const float* __restrict__ dwb, _Float16* __restrict__ dwo) {
    __shared__ FusedSm sm;
    int bid = blockIdx.x;
    int tid = threadIdx.x;

    if (bid < NB * DIM) {
        // ---------- depthwise 3x3x3 conv ----------
        int b = bid / DIM, c = bid % DIM;
        float* tile = sm.dwtile;
        const _Float16* src = vt + (size_t)(b * DIM + c) * NTOK;
        for (int i = tid * 8; i < NTOK; i += 2048) {
            f16x8 v8 = *(const f16x8a*)(src + i);
#pragma unroll
            for (int m = 0; m < 8; ++m) tile[i + m] = (float)v8[m];
        }
        float wreg[27];
#pragma unroll
        for (int i = 0; i < 27; ++i) wreg[i] = dww[c * 27 + i];
        float bias = dwb[c];
        __syncthreads();
        for (int i = tid; i < NTOK; i += 256) {
            int d = i >> 8, h = (i >> 4) & 15, w = i & 15;
            float acc = bias;
#pragma unroll
            for (int kd = 0; kd < 3; ++kd) {
                int dz = d + kd - 1; if (dz < 0 || dz > 15) continue;
#pragma unroll
                for (int kh = 0; kh < 3; ++kh) {
                    int hz = h + kh - 1; if (hz < 0 || hz > 15) continue;
#pragma unroll
                    for (int kw = 0; kw < 3; ++kw) {
                        int wz = w + kw - 1; if (wz < 0 || wz > 15) continue;
                        acc += tile[(dz * 16 + hz) * 16 + wz] * wreg[(kd * 3 + kh) * 3 + kw];
                    }
                }
            }
            dwo[(size_t)(b * DIM + c) * NTOK + i] = (_Float16)acc;
        }
        return;
    }

    // ---------- attention via MFMA (f16 frags, fp32 acc, ones-row lsum) ----------
    int abid = bid - NB * DIM;                // ((b*32+h)*16 + tb)
    int tb = abid & 15, bh = abid >> 4;
    int lane = tid & 63, wid = tid >> 6;

    const aint4* kvb = (const aint4*)(kvs + (size_t)bh * KTOP * 16);
    for (int i = tid; i < KTOP; i += 256) {
        int4 kk = kvb[2 * i];
        int4 vv = kvb[2 * i + 1];
        *(aint4*)&sm.a.Klds[i][0] = kk;
        union { int4 i4; unsigned short u[8]; } uv; uv.i4 = vv;
        unsigned short* vcol = (unsigned short*)&sm.a.Vt[0][0];
#pragma unroll
        for (int d = 0; d < 8; ++d)
            vcol[d * (KTOP + 8) + i] = uv.u[d];
        vcol[8 * (KTOP + 8) + i] = 0x3C00;    // f16 1.0
    }

    int qblk = tb * 256 + wid * 64;
    int qcol = lane & 15;
    const _Float16* qb = qh + (size_t)bh * NTOK * 8;
    f16x8 qf[4];
#pragma unroll
    for (int t = 0; t < 4; ++t)
        qf[t] = *(const f16x8a*)(qb + (size_t)(qblk + t * 16 + qcol) * 8);
    __syncthreads();

    int g = lane >> 4;
    _Float16* pw = &sm.a.Plds[wid][(lane & 15) * 40 + g * 4];
    const f16x8a* pr = (const f16x8a*)&sm.a.Plds[wid][(lane & 15) * 40 + g * 8];
    int vr15 = lane & 15; if (vr15 > 8) vr15 = 8;
    const _Float16* vrow = &sm.a.Vt[vr15][g * 8];

    f32x4 acc[4];
#pragma unroll
    for (int t = 0; t < 4; ++t) acc[t] = (f32x4){0.f, 0.f, 0.f, 0.f};
    const f32x4 z = {0.f, 0.f, 0.f, 0.f};

    for (int ks = 0; ks < 16; ++ks) {
        f16x8 ka = {}, kb = {};
        if (lane < 16) {
            ka = *(const f16x8a*)&sm.a.Klds[ks * 32 + lane][0];
            kb = *(const f16x8a*)&sm.a.Klds[ks * 32 + 16 + lane][0];
        }
        f16x8 vf = *(const f16x8a*)&vrow[ks * 32];
#pragma unroll
        for (int t = 0; t < 4; ++t) {
            f32x4 c0 = __builtin_amdgcn_mfma_f32_16x16x32_f16(ka, qf[t], z, 0, 0, 0);
            f32x4 c1 = __builtin_amdgcn_mfma_f32_16x16x32_f16(kb, qf[t], z, 0, 0, 0);
            float p0 = __builtin_amdgcn_exp2f(c0[0]);
            float p1 = __builtin_amdgcn_exp2f(c0[1]);
            float p2 = __builtin_amdgcn_exp2f(c0[2]);
            float p3 = __builtin_amdgcn_exp2f(c0[3]);
            float p4 = __builtin_amdgcn_exp2f(c1[0]);
            float p5 = __builtin_amdgcn_exp2f(c1[1]);
            float p6 = __builtin_amdgcn_exp2f(c1[2]);
            float p7 = __builtin_amdgcn_exp2f(c1[3]);
            union { h16x2 h2[2]; uint2 u2; } w01, w23;
            w01.h2[0] = __builtin_amdgcn_cvt_pkrtz(p0, p1);
            w01.h2[1] = __builtin_amdgcn_cvt_pkrtz(p2, p3);
            w23.h2[0] = __builtin_amdgcn_cvt_pkrtz(p4, p5);
            w23.h2[1] = __builtin_amdgcn_cvt_pkrtz(p6, p7);
            *(auint2*)pw        = w01.u2;     // tile0 rows g*4..+3
            *(auint2*)(pw + 16) = w23.u2;     // tile1 rows 16+g*4..+3
            f16x8 pf = *pr;                   // B-frag: rows g*8..+7, col q
            acc[t] = __builtin_amdgcn_mfma_f32_16x16x32_f16(vf, pf, acc[t], 0, 0, 0);
        }
    }

    int b = bh >> 5, h = bh & 31;
#pragma unroll
    for (int t = 0; t < 4; ++t) {
        float ls = __shfl(acc[t][0], 32 + (lane & 15));
        float inv = 1.0f / ls;
        if (lane < 32) {
            int n = qblk + t * 16 + (lane & 15);
            int dbase = (lane >> 4) * 4;
            _Float16* op = at + ((size_t)(b * DIM + h * HDIM + dbase)) * NTOK + n;
            op[0]        = (_Float16)(acc[t][0] * inv);
            op[NTOK]     = (_Float16)(acc[t][1] * inv);
            op[2 * NTOK] = (_Float16)(acc[t][2] * inv);
            op[3 * NTOK] = (_Float16)(acc[t][3] * inv);
        }
    }
}

// ---------------- 6+8. fused proj + pw GEMM: out = proj(at)+pw(dw)+biases ------
__global__ __launch_bounds__(256)
void gemm_dual(const _Float16* __restrict__ At, const _Float16* __restrict__ Dw,
               const float* __restrict__ Wp_, const float* __restrict__ Wq_,
               const float* __restrict__ bp_, const float* __restrict__ bq_,
               float* __restrict__ outbase) {
    __shared__ _Float16 Wp[64][72];
    __shared__ _Float16 Wq[64][72];
    __shared__ _Float16 Xa[64][72];
    __shared__ _Float16 Xd[64][72];
    int b  = blockIdx.z;
    int j0 = blockIdx.x * 64;
    int n0 = blockIdx.y * 64;
    int t  = threadIdx.x;
    int lane = t & 63, wid = t >> 6;
    int wj = wid >> 1, wn = wid & 1;
    const _Float16* Aa = At + (size_t)b * DIM * NTOK;
    const _Float16* Ad = Dw + (size_t)b * DIM * NTOK;

    f32x4 acc00 = {0.f,0.f,0.f,0.f}, acc01 = {0.f,0.f,0.f,0.f};
    f32x4 acc10 = {0.f,0.f,0.f,0.f}, acc11 = {0.f,0.f,0.f,0.f};

    for (int ks = 0; ks < 4; ++ks) {
        int c0 = ks * 64;
        if (ks) __syncthreads();
#pragma unroll
        for (int r = 0; r < 4; ++r) {
            int j  = r * 16 + (t >> 4);
            int cq = (t & 15) * 4;
            float4 wv = *(const float4*)(Wp_ + (size_t)(j0 + j) * DIM + c0 + cq);
            float4 wu = *(const float4*)(Wq_ + (size_t)(j0 + j) * DIM + c0 + cq);
            union { h16x2 h2[2]; uint2 u2; } p, q;
            p.h2[0] = __builtin_amdgcn_cvt_pkrtz(wv.x, wv.y);
            p.h2[1] = __builtin_amdgcn_cvt_pkrtz(wv.z, wv.w);
            q.h2[0] = __builtin_amdgcn_cvt_pkrtz(wu.x, wu.y);
            q.h2[1] = __builtin_amdgcn_cvt_pkrtz(wu.z, wu.w);
            *(auint2*)&Wp[j][cq] = p.u2;
            *(auint2*)&Wq[j][cq] = q.u2;
        }
        {
            int nl = t & 63, cb = (t >> 6) * 16;
            union { unsigned short u[16]; int4 i4[2]; } ua, ud;
#pragma unroll
            for (int i = 0; i < 16; ++i) {
                ua.u[i] = *(const unsigned short*)(Aa + (size_t)(c0 + cb + i) * NTOK + n0 + nl);
                ud.u[i] = *(const unsigned short*)(Ad + (size_t)(c0 + cb + i) * NTOK + n0 + nl);
            }
            *(aint4*)&Xa[nl][cb]     = ua.i4[0];
            *(aint4*)&Xa[nl][cb + 8] = ua.i4[1];
            *(aint4*)&Xd[nl][cb]     = ud.i4[0];
            *(aint4*)&Xd[nl][cb + 8] = ud.i4[1];
        }
        __syncthreads();
        const _Float16* wPa = &Wp[wj * 32 + (lane & 15)][(lane >> 4) * 8];
        const _Float16* wQa = &Wq[wj * 32 + (lane & 15)][(lane >> 4) * 8];
        const _Float16* xAa = &Xa[wn * 32 + (lane & 15)][(lane >> 4) * 8];
        const _Float16* xDa = &Xd[wn * 32 + (lane & 15)][(lane >> 4) * 8];
#pragma unroll
        for (int s = 0; s < 2; ++s) {
            f16x8 p0 = *(const f16x8a*)(wPa + s * 32);
            f16x8 p1 = *(const f16x8a*)(wPa + 16 * 72 + s * 32);
            f16x8 q0 = *(const f16x8a*)(wQa + s * 32);
            f16x8 q1 = *(const f16x8a*)(wQa + 16 * 72 + s * 32);
            f16x8 a0 = *(const f16x8a*)(xAa + s * 32);
            f16x8 a1 = *(const f16x8a*)(xAa + 16 * 72 + s * 32);
            f16x8 d0 = *(const f16x8a*)(xDa + s * 32);
            f16x8 d1 = *(const f16x8a*)(xDa + 16 * 72 + s * 32);
            acc00 = __builtin_amdgcn_mfma_f32_16x16x32_f16(p0, a0, acc00, 0, 0, 0);
            acc00 = __builtin_amdgcn_mfma_f32_16x16x32_f16(q0, d0, acc00, 0, 0, 0);
            acc01 = __builtin_amdgcn_mfma_f32_16x16x32_f16(p0, a1, acc01, 0, 0, 0);
            acc01 = __builtin_amdgcn_mfma_f32_16x16x32_f16(q0, d1, acc01, 0, 0, 0);
            acc10 = __builtin_amdgcn_mfma_f32_16x16x32_f16(p1, a0, acc10, 0, 0, 0);
            acc10 = __builtin_amdgcn_mfma_f32_16x16x32_f16(q1, d0, acc10, 0, 0, 0);
            acc11 = __builtin_amdgcn_mfma_f32_16x16x32_f16(p1, a1, acc11, 0, 0, 0);
            acc11 = __builtin_amdgcn_mfma_f32_16x16x32_f16(q1, d1, acc11, 0, 0, 0);
        }
    }

    int jb0 = j0 + wj * 32 + (lane >> 4) * 4;
    int nn0 = n0 + wn * 32 + (lane & 15);
#pragma unroll
    for (int jt = 0; jt < 2; ++jt) {
#pragma unroll
        for (int nt = 0; nt < 2; ++nt) {
            f32x4 ac = (jt == 0) ? (nt == 0 ? acc00 : acc01)
                                 : (nt == 0 ? acc10 : acc11);
            int jb = jb0 + jt * 16;
            int n  = nn0 + nt * 16;
            float4 bp = *(const float4*)(bp_ + jb);
            float4 bq = *(const float4*)(bq_ + jb);
            float* op = outbase + (size_t)(b * DIM + jb) * NTOK + n;
            op[0]        = ac[0] + bp.x + bq.x;
            op[NTOK]     = ac[1] + bp.y + bq.y;
            op[2 * NTOK] = ac[2] + bp.z + bq.z;
            op[3 * NTOK] = ac[3] + bp.w + bq.w;
        }
    }
}

extern "C" void kernel_launch(void* const* d_in, const int* in_sizes, int n_in,
                              void* d_out, int out_size, void* d_ws, size_t ws_size,
                              hipStream_t stream) {
    const float* x      = (const float*)d_in[0];
    const float* spa_w  = (const float*)d_in[1];
    const float* qkv_w  = (const float*)d_in[2];
    const float* proj_w = (const float*)d_in[3];
    const float* proj_b = (const float*)d_in[4];
    const float* dw_w   = (const float*)d_in[5];
    const float* dw_b   = (const float*)d_in[6];
    const float* pw_w   = (const float*)d_in[7];
    const float* pw_b   = (const float*)d_in[8];
    float* out = (float*)d_out;
    float* ws  = (float*)d_ws;

    float* am      = ws + AM_OFF;
    float* scores  = ws + SC_OFF;
    _Float16* vth  = (_Float16*)(ws + VT_OFF);
    _Float16* ath  = (_Float16*)(ws + AT_OFF);
    _Float16* dwh  = (_Float16*)(ws + DW_OFF);
    _Float16* kvs  = (_Float16*)(ws + KVS_OFF);
    _Float16* khv  = (_Float16*)(ws + KHV_OFF);
    _Float16* qh   = (_Float16*)(ws + QH_OFF);

    gemm_qkv<<<dim3(12, 64, NB), 256, 0, stream>>>(x, qkv_w, khv, vth, qh, am);
    spa_conv<<<NB * 16, 256, 0, stream>>>(am, spa_w, scores);
    kv_topk<<<NB * NHEAD, 256, 0, stream>>>(scores, khv, kvs);
    attn_dw<<<NB * DIM + NB * NHEAD * 16, 256, 0, stream>>>(qh, kvs, ath,
                                                            vth, dw_w, dw_b, dwh);
    gemm_dual<<<dim3(4, 64, NB), 256, 0, stream>>>(ath, dwh, proj_w, pw_w,
                                                   proj_b, pw_b, out);
}

// Round 11
// 88.109 us; speedup vs baseline: 1.3521x; 1.0117x over previous
//
#include <hip/hip_runtime.h>
#include <math.h>

#define DIM    256
#define NHEAD  32
#define HDIM   8
#define KTOP   512
#define NTOK   4096   // 16*16*16
#define NB     2

typedef float    f32x4  __attribute__((ext_vector_type(4)));
typedef _Float16 f16x8  __attribute__((ext_vector_type(8)));
typedef __fp16   h16x2  __attribute__((ext_vector_type(2)));   // cvt_pkrtz return type
typedef f16x8 f16x8a __attribute__((may_alias));
typedef int4  aint4  __attribute__((may_alias));
typedef uint2 auint2 __attribute__((may_alias));

// ---------------- workspace layout (float offsets) ----------------
#define AM_OFF   0                         // [B][2][NTOK] avg/max fp32
#define SC_OFF   16384                     // [B][NTOK] scores fp32
#define VT_OFF   24576                     // [B][DIM][NTOK] f16 v c-major
#define AT_OFF   (VT_OFF + 1048576)        // [B][DIM][NTOK] f16 attn out
#define DW_OFF   (AT_OFF + 1048576)        // [B][DIM][NTOK] f16 dwconv out
#define KVS_OFF  (DW_OFF + 1048576)        // [B*32][512][16] f16 gathered K/V
#define KHV_OFF  (KVS_OFF + 131072)        // [B][NTOK][512] f16 (k:0-255, v:256-511)
#define QH_OFF   (KHV_OFF + 2097152)       // [B*32][NTOK][8] f16 q pre-scaled

// ---------------- 2. 7x7x7 conv (2->1 ch) + sigmoid, LDS-staged ----------------
__global__ __launch_bounds__(256)
void spa_conv(const float* __restrict__ am, const float* __restrict__ w,
              float* __restrict__ scores) {
    __shared__ float tile[2][7][22][24];   // 28.9 KB
    __shared__ float red[4][256];
    int bd = blockIdx.x;          // b*16 + d
    int b = bd >> 4, d = bd & 15;
    int tid = threadIdx.x;
    float4* t4 = (float4*)&tile[0][0][0][0];
    for (int i = tid; i < (2 * 7 * 22 * 24) / 4; i += 256)
        t4[i] = (float4){0.f, 0.f, 0.f, 0.f};
    __syncthreads();
    for (int it = 0; it < 14; ++it) {
        int j = it * 256 + tid;
        int ci = (j >= 1792) ? 1 : 0;
        int r = j - ci * 1792;
        int kd = r >> 8, pos = r & 255;
        int dz = d + kd - 3;
        if ((unsigned)dz < 16u)
            tile[ci][kd][(pos >> 4) + 3][(pos & 15) + 3] =
                am[((size_t)b * 2 + ci) * NTOK + dz * 256 + pos];
    }
    __syncthreads();
    int h  = (tid >> 2) & 15;
    int wg = tid & 3;
    int s  = __builtin_amdgcn_readfirstlane(tid >> 6);
    int pstart = (s < 2) ? s * 4 : 8 + (s - 2) * 3;
    int pcnt   = (s < 2) ? 4 : 3;
    float o0 = 0.f, o1 = 0.f, o2 = 0.f, o3 = 0.f;
    for (int pp = 0; pp < 4; ++pp) {
        if (pp >= pcnt) break;
        int p = pstart + pp;
        int ci = (p >= 7) ? 1 : 0;
        int kd = p - ci * 7;
        const float* wrow = w + (ci * 343 + kd * 49);
#pragma unroll
        for (int kh = 0; kh < 7; ++kh) {
            const float* trow = &tile[ci][kd][h + kh][wg * 4];
            float4 r0 = *(const float4*)(trow);
            float4 r1 = *(const float4*)(trow + 4);
            float4 r2 = *(const float4*)(trow + 8);
            float rr[12] = {r0.x, r0.y, r0.z, r0.w, r1.x, r1.y, r1.z, r1.w,
                            r2.x, r2.y, r2.z, r2.w};
#pragma unroll
            for (int kw = 0; kw < 7; ++kw) {
                float wv = wrow[kh * 7 + kw];
                o0 += rr[kw + 0] * wv;
                o1 += rr[kw + 1] * wv;
                o2 += rr[kw + 2] * wv;
                o3 += rr[kw + 3] * wv;
            }
        }
    }
    int q = h * 16 + wg * 4;
    red[s][q + 0] = o0; red[s][q + 1] = o1; red[s][q + 2] = o2; red[s][q + 3] = o3;
    __syncthreads();
    float acc = red[0][tid] + red[1][tid] + red[2][tid] + red[3][tid];
    float sg = 1.0f / (1.0f + expf(-acc));
    scores[(size_t)b * NTOK + d * 256 + tid] = sg;
}

// ---------------- 4. qkv MFMA GEMM, 64j x 128n tile (+fused mean/max) -----------
// grid (12 j, 32 n, B), j fastest (A-tile L2 reuse).
// j<256 (q): qh[b*32+h][n][8] f16 PRE-SCALED by 8^-0.5*log2e.
// j>=256 (k,v): khv[b][n][j-256] f16. j>=512: also vt[b][c][n] f16.
__global__ __launch_bounds__(256)
void gemm_qkv(const float* __restrict__ A_, const float* __restrict__ W,
              _Float16* __restrict__ khv, _Float16* __restrict__ vt,
              _Float16* __restrict__ qh, float* __restrict__ am) {
    __shared__ _Float16 Ws_h[64][72];       // 9.2 KB
    __shared__ _Float16 Xs[128][72];        // 18.4 KB
    __shared__ float ams[2][2][128];        // 2 KB
    int b  = blockIdx.z;
    int j0 = blockIdx.x * 64;
    int n0 = blockIdx.y * 128;
    int t  = threadIdx.x;
    int lane = t & 63, wid = t >> 6;
    int wj = wid >> 1, wn = wid & 1;        // wave: rows wj*32, cols wn*64
    const float* A = A_ + (size_t)b * DIM * NTOK;
    bool do_am = (blockIdx.x == 0);

    f32x4 acc[2][4];
#pragma unroll
    for (int i = 0; i < 2; ++i)
#pragma unroll
        for (int j = 0; j < 4; ++j) acc[i][j] = (f32x4){0.f, 0.f, 0.f, 0.f};
    float amsum = 0.f, ammax = -1e30f;

    for (int ks = 0; ks < 4; ++ks) {
        int c0 = ks * 64;
        if (ks) __syncthreads();
        // ---- stage W tile 64j x 64c ----
#pragma unroll
        for (int r = 0; r < 4; ++r) {
            int j  = r * 16 + (t >> 4);
            int cq = (t & 15) * 4;
            float4 wv = *(const float4*)(W + (size_t)(j0 + j) * DIM + c0 + cq);
            union { h16x2 h2[2]; uint2 u2; } p;
            p.h2[0] = __builtin_amdgcn_cvt_pkrtz(wv.x, wv.y);
            p.h2[1] = __builtin_amdgcn_cvt_pkrtz(wv.z, wv.w);
            *(auint2*)&Ws_h[j][cq] = p.u2;
        }
        // ---- stage X tile transposed: Xs[n][c], 128n x 64c ----
        {
            int nl = t & 127, cb = (t >> 7) * 32;
            float v[32];
#pragma unroll
            for (int i = 0; i < 32; ++i)
                v[i] = A[(size_t)(c0 + cb + i) * NTOK + n0 + nl];
            if (do_am) {
#pragma unroll
                for (int i = 0; i < 32; ++i) {
                    amsum += v[i]; ammax = fmaxf(ammax, v[i]);
                }
            }
            union { h16x2 h2[16]; int4 i4[4]; } u;
#pragma unroll
            for (int m = 0; m < 16; ++m)
                u.h2[m] = __builtin_amdgcn_cvt_pkrtz(v[2 * m], v[2 * m + 1]);
#pragma unroll
            for (int m = 0; m < 4; ++m)
                *(aint4*)&Xs[nl][cb + m * 8] = u.i4[m];
        }
        __syncthreads();
        // ---- compute: 2x4 16x16 tiles per wave ----
        const _Float16* wA = &Ws_h[wj * 32 + (lane & 15)][(lane >> 4) * 8];
        const _Float16* xB = &Xs [wn * 64 + (lane & 15)][(lane >> 4) * 8];
#pragma unroll
        for (int s = 0; s < 2; ++s) {
            f16x8 a0 = *(const f16x8a*)(wA + s * 32);
            f16x8 a1 = *(const f16x8a*)(wA + 16 * 72 + s * 32);
            f16x8 b0 = *(const f16x8a*)(xB + s * 32);
            f16x8 b1 = *(const f16x8a*)(xB + 16 * 72 + s * 32);
            f16x8 b2 = *(const f16x8a*)(xB + 32 * 72 + s * 32);
            f16x8 b3 = *(const f16x8a*)(xB + 48 * 72 + s * 32);
            acc[0][0] = __builtin_amdgcn_mfma_f32_16x16x32_f16(a0, b0, acc[0][0], 0, 0, 0);
            acc[0][1] = __builtin_amdgcn_mfma_f32_16x16x32_f16(a0, b1, acc[0][1], 0, 0, 0);
            acc[0][2] = __builtin_amdgcn_mfma_f32_16x16x32_f16(a0, b2, acc[0][2], 0, 0, 0);
            acc[0][3] = __builtin_amdgcn_mfma_f32_16x16x32_f16(a0, b3, acc[0][3], 0, 0, 0);
            acc[1][0] = __builtin_amdgcn_mfma_f32_16x16x32_f16(a1, b0, acc[1][0], 0, 0, 0);
            acc[1][1] = __builtin_amdgcn_mfma_f32_16x16x32_f16(a1, b1, acc[1][1], 0, 0, 0);
            acc[1][2] = __builtin_amdgcn_mfma_f32_16x16x32_f16(a1, b2, acc[1][2], 0, 0, 0);
            acc[1][3] = __builtin_amdgcn_mfma_f32_16x16x32_f16(a1, b3, acc[1][3], 0, 0, 0);
        }
    }

    if (do_am) {
        int nl = t & 127, cbg = t >> 7;
        ams[0][cbg][nl] = amsum;
        ams[1][cbg][nl] = ammax;
        __syncthreads();
        if (t < 128) {
            float ss = ams[0][0][t] + ams[0][1][t];
            float mm = fmaxf(ams[1][0][t], ams[1][1][t]);
            am[(size_t)b * 2 * NTOK + n0 + t]        = ss * (1.0f / DIM);
            am[(size_t)b * 2 * NTOK + NTOK + n0 + t] = mm;
        }
    }

    const float qsc = 0.35355339059327373f * 1.4426950408889634f;
    int jb0 = j0 + wj * 32 + (lane >> 4) * 4;
    int nn0 = n0 + wn * 64 + (lane & 15);
#pragma unroll
    for (int jt = 0; jt < 2; ++jt) {
#pragma unroll
        for (int nt = 0; nt < 4; ++nt) {
            f32x4 ac = acc[jt][nt];
            int jb = jb0 + jt * 16;
            int n  = nn0 + nt * 16;
            if (jb < 256) {
                int hh = jb >> 3, dq = jb & 7;
                union { h16x2 h2[2]; uint2 u2; } p;
                p.h2[0] = __builtin_amdgcn_cvt_pkrtz(ac[0] * qsc, ac[1] * qsc);
                p.h2[1] = __builtin_amdgcn_cvt_pkrtz(ac[2] * qsc, ac[3] * qsc);
                *(auint2*)(qh + ((size_t)((b << 5) | hh) * NTOK + n) * 8 + dq) = p.u2;
            } else {
                union { h16x2 h2[2]; uint2 u2; } p;
                p.h2[0] = __builtin_amdgcn_cvt_pkrtz(ac[0], ac[1]);
                p.h2[1] = __builtin_amdgcn_cvt_pkrtz(ac[2], ac[3]);
                *(auint2*)(khv + ((size_t)b * NTOK + n) * 512 + (jb - 256)) = p.u2;
                if (jb >= 512) {
                    _Float16* vp = vt + (size_t)(b * DIM + jb - 512) * NTOK + n;
                    vp[0]        = (_Float16)ac[0];
                    vp[NTOK]     = (_Float16)ac[1];
                    vp[2 * NTOK] = (_Float16)ac[2];
                    vp[3 * NTOK] = (_Float16)ac[3];
                }
            }
        }
    }
}

// ---------------- 3+4b. fused top-512 radix-select + K/V gather per (b,h) -------
__global__ __launch_bounds__(256)
void kv_topk(const float* __restrict__ scores, const _Float16* __restrict__ khv,
             _Float16* __restrict__ kvs) {
    __shared__ int wsum[4];
    __shared__ unsigned int s_thr;
    __shared__ int s_cnt;
    __shared__ unsigned int tiem[NTOK / 32];
    __shared__ int tiep[NTOK / 32];
    __shared__ int sel[KTOP];
    int bh = blockIdx.x;           // b*32 + h
    int h = bh & 31, b = bh >> 5;
    int tid = threadIdx.x, lane = tid & 63, wid = tid >> 6;
    unsigned int v[16];
#pragma unroll
    for (int j = 0; j < 16; ++j)
        v[j] = __float_as_uint(scores[b * NTOK + j * 256 + tid]);  // positive, <1.0
    if (tid == 0) { s_thr = 0u; s_cnt = 0; }
    if (tid < NTOK / 32) tiem[tid] = 0u;
    __syncthreads();
    for (int bit = 29; bit >= 0; --bit) {
        unsigned int test = s_thr | (1u << bit);
        int c = 0;
#pragma unroll
        for (int j = 0; j < 16; ++j)
            c += (int)__popcll(__ballot(v[j] >= test));
        if (lane == 0) wsum[wid] = c;
        __syncthreads();
        if (tid == 0) {
            int tot = wsum[0] + wsum[1] + wsum[2] + wsum[3];
            if (tot >= KTOP) s_thr = test;
        }
        __syncthreads();
    }
    unsigned int T = s_thr;
    {
        int c = 0;
#pragma unroll
        for (int j = 0; j < 16; ++j)
            c += (int)__popcll(__ballot(v[j] > T));
        if (lane == 0) wsum[wid] = c;
    }
    __syncthreads();
    int cnt_gt = wsum[0] + wsum[1] + wsum[2] + wsum[3];
    int krem = KTOP - cnt_gt;
#pragma unroll
    for (int j = 0; j < 16; ++j) {
        int i = j * 256 + tid;
        if (v[j] > T) sel[atomicAdd(&s_cnt, 1)] = i;
        if (v[j] == T) atomicOr(&tiem[i >> 5], 1u << (i & 31));
    }
    __syncthreads();
    if (tid == 0) {
        int c = 0;
        for (int w2 = 0; w2 < NTOK / 32; ++w2) { tiep[w2] = c; c += __popc(tiem[w2]); }
    }
    __syncthreads();
#pragma unroll
    for (int j = 0; j < 16; ++j) {
        int i = j * 256 + tid;
        if (v[j] == T) {
            int r = tiep[i >> 5] + __popc(tiem[i >> 5] & ((1u << (i & 31)) - 1u));
            if (r < krem) sel[cnt_gt + r] = i;
        }
    }
    __syncthreads();
    aint4* dst = (aint4*)(kvs + (size_t)bh * KTOP * 16);
    const _Float16* src = khv + (size_t)b * NTOK * 512;
    for (int i = tid; i < KTOP; i += 256) {
        int tok = sel[i];
        aint4 k16 = *(const aint4*)(src + (size_t)tok * 512 + h * 8);
        aint4 v16 = *(const aint4*)(src + (size_t)tok * 512 + 256 + h * 8);
        dst[2 * i]     = k16;
        dst[2 * i + 1] = v16;
    }
}

// ---------------- 5+7. fused attention + depthwise conv (independent works) -----
struct AttnSm {
    _Float16 Klds[KTOP][8];        // [k][d] 16B rows
    _Float16 Vt[9][KTOP + 8];      // [d][k]; row 8 = ones (lsum trick)
    _Float16 Plds[4][16 * 40];     // per-wave [q][40]
};
union FusedSm { AttnSm a; float dwtile[NTOK]; };

__global__ __launch_bounds__(256)
void attn_dw(const _Float16* __restrict__ qh, const _Float16* __restrict__ kvs,
             _Float16* __restrict__ at,
             const _Float16* __restrict__ vt, const float* __restrict__ dww,
             const float* __restrict__ dwb, _Float16* __restrict__ dwo) {
    __shared__ FusedSm sm;
    int bid = blockIdx.x;
    int tid = threadIdx.x;

    if (bid < NB * DIM) {
        // ---------- depthwise 3x3x3 conv ----------
        int b = bid / DIM, c = bid % DIM;
        float* tile = sm.dwtile;
        const _Float16* src = vt + (size_t)(b * DIM + c) * NTOK;
        for (int i = tid * 8; i < NTOK; i += 2048) {
            f16x8 v8 = *(const f16x8a*)(src + i);
#pragma unroll
            for (int m = 0; m < 8; ++m) tile[i + m] = (float)v8[m];
        }
        float wreg[27];
#pragma unroll
        for (int i = 0; i < 27; ++i) wreg[i] = dww[c * 27 + i];
        float bias = dwb[c];
        __syncthreads();
        for (int i = tid; i < NTOK; i += 256) {
            int d = i >> 8, h = (i >> 4) & 15, w = i & 15;
            float acc = bias;
#pragma unroll
            for (int kd = 0; kd < 3; ++kd) {
                int dz = d + kd - 1; if (dz < 0 || dz > 15) continue;
#pragma unroll
                for (int kh = 0; kh < 3; ++kh) {
                    int hz = h + kh - 1; if (hz < 0 || hz > 15) continue;
#pragma unroll
                    for (int kw = 0; kw < 3; ++kw) {
                        int wz = w + kw - 1; if (wz < 0 || wz > 15) continue;
                        acc += tile[(dz * 16 + hz) * 16 + wz] * wreg[(kd * 3 + kh) * 3 + kw];
                    }
                }
            }
            dwo[(size_t)(b * DIM + c) * NTOK + i] = (_Float16)acc;
        }
        return;
    }

    // ---------- attention via MFMA (f16 frags, fp32 acc, ones-row lsum) ----------
    int abid = bid - NB * DIM;                // ((b*32+h)*16 + tb)
    int tb = abid & 15, bh = abid >> 4;
    int lane = tid & 63, wid = tid >> 6;

    const aint4* kvb = (const aint4*)(kvs + (size_t)bh * KTOP * 16);
    for (int i = tid; i < KTOP; i += 256) {
        int4 kk = kvb[2 * i];
        int4 vv = kvb[2 * i + 1];
        *(aint4*)&sm.a.Klds[i][0] = kk;
        union { int4 i4; unsigned short u[8]; } uv; uv.i4 = vv;
        unsigned short* vcol = (unsigned short*)&sm.a.Vt[0][0];
#pragma unroll
        for (int d = 0; d < 8; ++d)
            vcol[d * (KTOP + 8) + i] = uv.u[d];
        vcol[8 * (KTOP + 8) + i] = 0x3C00;    // f16 1.0
    }

    int qblk = tb * 256 + wid * 64;
    int qcol = lane & 15;
    const _Float16* qb = qh + (size_t)bh * NTOK * 8;
    f16x8 qf[4];
#pragma unroll
    for (int t = 0; t < 4; ++t)
        qf[t] = *(const f16x8a*)(qb + (size_t)(qblk + t * 16 + qcol) * 8);
    __syncthreads();

    int g = lane >> 4;
    _Float16* pw = &sm.a.Plds[wid][(lane & 15) * 40 + g * 4];
    const f16x8a* pr = (const f16x8a*)&sm.a.Plds[wid][(lane & 15) * 40 + g * 8];
    int vr15 = lane & 15; if (vr15 > 8) vr15 = 8;
    const _Float16* vrow = &sm.a.Vt[vr15][g * 8];

    f32x4 acc[4];
#pragma unroll
    for (int t = 0; t < 4; ++t) acc[t] = (f32x4){0.f, 0.f, 0.f, 0.f};
    const f32x4 z = {0.f, 0.f, 0.f, 0.f};

    for (int ks = 0; ks < 16; ++ks) {
        f16x8 ka = {}, kb = {};
        if (lane < 16) {
            ka = *(const f16x8a*)&sm.a.Klds[ks * 32 + lane][0];
            kb = *(const f16x8a*)&sm.a.Klds[ks * 32 + 16 + lane][0];
        }
        f16x8 vf = *(const f16x8a*)&vrow[ks * 32];
#pragma unroll
        for (int t = 0; t < 4; ++t) {
            f32x4 c0 = __builtin_amdgcn_mfma_f32_16x16x32_f16(ka, qf[t], z, 0, 0, 0);
            f32x4 c1 = __builtin_amdgcn_mfma_f32_16x16x32_f16(kb, qf[t], z, 0, 0, 0);
            float p0 = __builtin_amdgcn_exp2f(c0[0]);
            float p1 = __builtin_amdgcn_exp2f(c0[1]);
            float p2 = __builtin_amdgcn_exp2f(c0[2]);
            float p3 = __builtin_amdgcn_exp2f(c0[3]);
            float p4 = __builtin_amdgcn_exp2f(c1[0]);
            float p5 = __builtin_amdgcn_exp2f(c1[1]);
            float p6 = __builtin_amdgcn_exp2f(c1[2]);
            float p7 = __builtin_amdgcn_exp2f(c1[3]);
            union { h16x2 h2[2]; uint2 u2; } w01, w23;
            w01.h2[0] = __builtin_amdgcn_cvt_pkrtz(p0, p1);
            w01.h2[1] = __builtin_amdgcn_cvt_pkrtz(p2, p3);
            w23.h2[0] = __builtin_amdgcn_cvt_pkrtz(p4, p5);
            w23.h2[1] = __builtin_amdgcn_cvt_pkrtz(p6, p7);
            *(auint2*)pw        = w01.u2;     // tile0 rows g*4..+3
            *(auint2*)(pw + 16) = w23.u2;     // tile1 rows 16+g*4..+3
            f16x8 pf = *pr;                   // B-frag: rows g*8..+7, col q
            acc[t] = __builtin_amdgcn_mfma_f32_16x16x32_f16(vf, pf, acc[t], 0, 0, 0);
        }
    }

    int b = bh >> 5, h = bh & 31;
#pragma unroll
    for (int t = 0; t < 4; ++t) {
        float ls = __shfl(acc[t][0], 32 + (lane & 15));
        float inv = 1.0f / ls;
        if (lane < 32) {
            int n = qblk + t * 16 + (lane & 15);
            int dbase = (lane >> 4) * 4;
            _Float16* op = at + ((size_t)(b * DIM + h * HDIM + dbase)) * NTOK + n;
            op[0]        = (_Float16)(acc[t][0] * inv);
            op[NTOK]     = (_Float16)(acc[t][1] * inv);
            op[2 * NTOK] = (_Float16)(acc[t][2] * inv);
            op[3 * NTOK] = (_Float16)(acc[t][3] * inv);
        }
    }
}

// ---------------- 6+8. fused proj + pw GEMM, 64j x 128n tile --------------------
__global__ __launch_bounds__(256)
void gemm_dual(const _Float16* __restrict__ At, const _Float16* __restrict__ Dw,
               const float* __restrict__ Wp_, const float* __restrict__ Wq_,
               const float* __restrict__ bp_, const float* __restrict__ bq_,
               float* __restrict__ outbase) {
    __shared__ _Float16 Wp[64][72];
    __shared__ _Float16 Wq[64][72];
    __shared__ _Float16 Xa[128][72];
    __shared__ _Float16 Xd[128][72];
    int b  = blockIdx.z;
    int j0 = blockIdx.x * 64;
    int n0 = blockIdx.y * 128;
    int t  = threadIdx.x;
    int lane = t & 63, wid = t >> 6;
    int wj = wid >> 1, wn = wid & 1;
    const _Float16* Aa = At + (size_t)b * DIM * NTOK;
    const _Float16* Ad = Dw + (size_t)b * DIM * NTOK;

    f32x4 acc[2][4];
#pragma unroll
    for (int i = 0; i < 2; ++i)
#pragma unroll
        for (int j = 0; j < 4; ++j) acc[i][j] = (f32x4){0.f, 0.f, 0.f, 0.f};

    for (int ks = 0; ks < 4; ++ks) {
        int c0 = ks * 64;
        if (ks) __syncthreads();
#pragma unroll
        for (int r = 0; r < 4; ++r) {
            int j  = r * 16 + (t >> 4);
            int cq = (t & 15) * 4;
            float4 wv = *(const float4*)(Wp_ + (size_t)(j0 + j) * DIM + c0 + cq);
            float4 wu = *(const float4*)(Wq_ + (size_t)(j0 + j) * DIM + c0 + cq);
            union { h16x2 h2[2]; uint2 u2; } p, q;
            p.h2[0] = __builtin_amdgcn_cvt_pkrtz(wv.x, wv.y);
            p.h2[1] = __builtin_amdgcn_cvt_pkrtz(wv.z, wv.w);
            q.h2[0] = __builtin_amdgcn_cvt_pkrtz(wu.x, wu.y);
            q.h2[1] = __builtin_amdgcn_cvt_pkrtz(wu.z, wu.w);
            *(auint2*)&Wp[j][cq] = p.u2;
            *(auint2*)&Wq[j][cq] = q.u2;
        }
        {
            int nl = t & 127, cb = (t >> 7) * 32;
            union { unsigned short u[32]; int4 i4[4]; } ua, ud;
#pragma unroll
            for (int i = 0; i < 32; ++i) {
                ua.u[i] = *(const unsigned short*)(Aa + (size_t)(c0 + cb + i) * NTOK + n0 + nl);
                ud.u[i] = *(const unsigned short*)(Ad + (size_t)(c0 + cb + i) * NTOK + n0 + nl);
            }
#pragma unroll
            for (int m = 0; m < 4; ++m) {
                *(aint4*)&Xa[nl][cb + m * 8] = ua.i4[m];
                *(aint4*)&Xd[nl][cb + m * 8] = ud.i4[m];
            }
        }
        __syncthreads();
        const _Float16* wPa = &Wp[wj * 32 + (lane & 15)][(lane >> 4) * 8];
        const _Float16* wQa = &Wq[wj * 32 + (lane & 15)][(lane >> 4) * 8];
        const _Float16* xAa = &Xa[wn * 64 + (lane & 15)][(lane >> 4) * 8];
        const _Float16* xDa = &Xd[wn * 64 + (lane & 15)][(lane >> 4) * 8];
#pragma unroll
        for (int s = 0; s < 2; ++s) {
            f16x8 p0 = *(const f16x8a*)(wPa + s * 32);
            f16x8 p1 = *(const f16x8a*)(wPa + 16 * 72 + s * 32);
            f16x8 q0 = *(const f16x8a*)(wQa + s * 32);
            f16x8 q1 = *(const f16x8a*)(wQa + 16 * 72 + s * 32);
#pragma unroll
            for (int nt = 0; nt < 4; ++nt) {
                f16x8 a = *(const f16x8a*)(xAa + nt * 16 * 72 + s * 32);
                f16x8 d = *(const f16x8a*)(xDa + nt * 16 * 72 + s * 32);
                acc[0][nt] = __builtin_amdgcn_mfma_f32_16x16x32_f16(p0, a, acc[0][nt], 0, 0, 0);
                acc[0][nt] = __builtin_amdgcn_mfma_f32_16x16x32_f16(q0, d, acc[0][nt], 0, 0, 0);
                acc[1][nt] = __builtin_amdgcn_mfma_f32_16x16x32_f16(p1, a, acc[1][nt], 0, 0, 0);
                acc[1][nt] = __builtin_amdgcn_mfma_f32_16x16x32_f16(q1, d, acc[1][nt], 0, 0, 0);
            }
        }
    }

    int jb0 = j0 + wj * 32 + (lane >> 4) * 4;
    int nn0 = n0 + wn * 64 + (lane & 15);
#pragma unroll
    for (int jt = 0; jt < 2; ++jt) {
#pragma unroll
        for (int nt = 0; nt < 4; ++nt) {
            f32x4 ac = acc[jt][nt];
            int jb = jb0 + jt * 16;
            int n  = nn0 + nt * 16;
            float4 bp = *(const float4*)(bp_ + jb);
            float4 bq = *(const float4*)(bq_ + jb);
            float* op = outbase + (size_t)(b * DIM + jb) * NTOK + n;
            op[0]        = ac[0] + bp.x + bq.x;
            op[NTOK]     = ac[1] + bp.y + bq.y;
            op[2 * NTOK] = ac[2] + bp.z + bq.z;
            op[3 * NTOK] = ac[3] + bp.w + bq.w;
        }
    }
}

extern "C" void kernel_launch(void* const* d_in, const int* in_sizes, int n_in,
                              void* d_out, int out_size, void* d_ws, size_t ws_size,
                              hipStream_t stream) {
    const float* x      = (const float*)d_in[0];
    const float* spa_w  = (const float*)d_in[1];
    const float* qkv_w  = (const float*)d_in[2];
    const float* proj_w = (const float*)d_in[3];
    const float* proj_b = (const float*)d_in[4];
    const float* dw_w   = (const float*)d_in[5];
    const float* dw_b   = (const float*)d_in[6];
    const float* pw_w   = (const float*)d_in[7];
    const float* pw_b   = (const float*)d_in[8];
    float* out = (float*)d_out;
    float* ws  = (float*)d_ws;

    float* am      = ws + AM_OFF;
    float* scores  = ws + SC_OFF;
    _Float16* vth  = (_Float16*)(ws + VT_OFF);
    _Float16* ath  = (_Float16*)(ws + AT_OFF);
    _Float16* dwh  = (_Float16*)(ws + DW_OFF);
    _Float16* kvs  = (_Float16*)(ws + KVS_OFF);
    _Float16* khv  = (_Float16*)(ws + KHV_OFF);
    _Float16* qh   = (_Float16*)(ws + QH_OFF);

    gemm_qkv<<<dim3(12, 32, NB), 256, 0, stream>>>(x, qkv_w, khv, vth, qh, am);
    spa_conv<<<NB * 16, 256, 0, stream>>>(am, spa_w, scores);
    kv_topk<<<NB * NHEAD, 256, 0, stream>>>(scores, khv, kvs);
    attn_dw<<<NB * DIM + NB * NHEAD * 16, 256, 0, stream>>>(qh, kvs, ath,
                                                            vth, dw_w, dw_b, dwh);
    gemm_dual<<<dim3(4, 32, NB), 256, 0, stream>>>(ath, dwh, proj_w, pw_w,
                                                   proj_b, pw_b, out);
}

// Round 12
// 86.260 us; speedup vs baseline: 1.3811x; 1.0214x over previous
//
#include <hip/hip_runtime.h>
#include <math.h>

#define DIM    256
#define NHEAD  32
#define HDIM   8
#define KTOP   512
#define NTOK   4096   // 16*16*16
#define NB     2

typedef float    f32x4  __attribute__((ext_vector_type(4)));
typedef _Float16 f16x8  __attribute__((ext_vector_type(8)));
typedef _Float16 f16x4  __attribute__((ext_vector_type(4)));
typedef __fp16   h16x2  __attribute__((ext_vector_type(2)));   // cvt_pkrtz return type
typedef f16x8 f16x8a __attribute__((may_alias));
typedef f16x4 f16x4a __attribute__((may_alias));
typedef int4  aint4  __attribute__((may_alias));
typedef uint2 auint2 __attribute__((may_alias));

// ---------------- workspace layout (float offsets) ----------------
#define AM_OFF   0                         // [B][2][NTOK] avg/max fp32
#define SC_OFF   16384                     // [B][NTOK] scores fp32
#define VT_OFF   24576                     // [B][DIM][NTOK] f16 v c-major
#define AT_OFF   (VT_OFF + 1048576)        // [B][DIM][NTOK] f16 attn out
#define DW_OFF   (AT_OFF + 1048576)        // [B][DIM][NTOK] f16 dwconv out
#define KVS_OFF  (DW_OFF + 1048576)        // [B*32][512][16] f16 gathered K/V
#define KHV_OFF  (KVS_OFF + 131072)        // [B][NTOK][512] f16 (k:0-255, v:256-511)
#define QH_OFF   (KHV_OFF + 2097152)       // [B*32][NTOK][8] f16 q pre-scaled

// ---------------- 2. 7x7x7 conv (2->1 ch) + sigmoid, LDS-staged ----------------
__global__ __launch_bounds__(256)
void spa_conv(const float* __restrict__ am, const float* __restrict__ w,
              float* __restrict__ scores) {
    __shared__ float tile[2][7][22][24];   // 28.9 KB
    __shared__ float red[4][256];
    int bd = blockIdx.x;          // b*16 + d
    int b = bd >> 4, d = bd & 15;
    int tid = threadIdx.x;
    float4* t4 = (float4*)&tile[0][0][0][0];
    for (int i = tid; i < (2 * 7 * 22 * 24) / 4; i += 256)
        t4[i] = (float4){0.f, 0.f, 0.f, 0.f};
    __syncthreads();
    for (int it = 0; it < 14; ++it) {
        int j = it * 256 + tid;
        int ci = (j >= 1792) ? 1 : 0;
        int r = j - ci * 1792;
        int kd = r >> 8, pos = r & 255;
        int dz = d + kd - 3;
        if ((unsigned)dz < 16u)
            tile[ci][kd][(pos >> 4) + 3][(pos & 15) + 3] =
                am[((size_t)b * 2 + ci) * NTOK + dz * 256 + pos];
    }
    __syncthreads();
    int h  = (tid >> 2) & 15;
    int wg = tid & 3;
    int s  = __builtin_amdgcn_readfirstlane(tid >> 6);
    int pstart = (s < 2) ? s * 4 : 8 + (s - 2) * 3;
    int pcnt   = (s < 2) ? 4 : 3;
    float o0 = 0.f, o1 = 0.f, o2 = 0.f, o3 = 0.f;
    for (int pp = 0; pp < 4; ++pp) {
        if (pp >= pcnt) break;
        int p = pstart + pp;
        int ci = (p >= 7) ? 1 : 0;
        int kd = p - ci * 7;
        const float* wrow = w + (ci * 343 + kd * 49);
#pragma unroll
        for (int kh = 0; kh < 7; ++kh) {
            const float* trow = &tile[ci][kd][h + kh][wg * 4];
            float4 r0 = *(const float4*)(trow);
            float4 r1 = *(const float4*)(trow + 4);
            float4 r2 = *(const float4*)(trow + 8);
            float rr[12] = {r0.x, r0.y, r0.z, r0.w, r1.x, r1.y, r1.z, r1.w,
                            r2.x, r2.y, r2.z, r2.w};
#pragma unroll
            for (int kw = 0; kw < 7; ++kw) {
                float wv = wrow[kh * 7 + kw];
                o0 += rr[kw + 0] * wv;
                o1 += rr[kw + 1] * wv;
                o2 += rr[kw + 2] * wv;
                o3 += rr[kw + 3] * wv;
            }
        }
    }
    int q = h * 16 + wg * 4;
    red[s][q + 0] = o0; red[s][q + 1] = o1; red[s][q + 2] = o2; red[s][q + 3] = o3;
    __syncthreads();
    float acc = red[0][tid] + red[1][tid] + red[2][tid] + red[3][tid];
    float sg = 1.0f / (1.0f + expf(-acc));
    scores[(size_t)b * NTOK + d * 256 + tid] = sg;
}

// ---------------- 4. qkv MFMA GEMM, 64j x 128n tile (+fused mean/max) -----------
__global__ __launch_bounds__(256)
void gemm_qkv(const float* __restrict__ A_, const float* __restrict__ W,
              _Float16* __restrict__ khv, _Float16* __restrict__ vt,
              _Float16* __restrict__ qh, float* __restrict__ am) {
    __shared__ _Float16 Ws_h[64][72];       // 9.2 KB
    __shared__ _Float16 Xs[128][72];        // 18.4 KB
    __shared__ float ams[2][2][128];        // 2 KB
    int b  = blockIdx.z;
    int j0 = blockIdx.x * 64;
    int n0 = blockIdx.y * 128;
    int t  = threadIdx.x;
    int lane = t & 63, wid = t >> 6;
    int wj = wid >> 1, wn = wid & 1;        // wave: rows wj*32, cols wn*64
    const float* A = A_ + (size_t)b * DIM * NTOK;
    bool do_am = (blockIdx.x == 0);

    f32x4 acc[2][4];
#pragma unroll
    for (int i = 0; i < 2; ++i)
#pragma unroll
        for (int j = 0; j < 4; ++j) acc[i][j] = (f32x4){0.f, 0.f, 0.f, 0.f};
    float amsum = 0.f, ammax = -1e30f;

    for (int ks = 0; ks < 4; ++ks) {
        int c0 = ks * 64;
        if (ks) __syncthreads();
#pragma unroll
        for (int r = 0; r < 4; ++r) {
            int j  = r * 16 + (t >> 4);
            int cq = (t & 15) * 4;
            float4 wv = *(const float4*)(W + (size_t)(j0 + j) * DIM + c0 + cq);
            union { h16x2 h2[2]; uint2 u2; } p;
            p.h2[0] = __builtin_amdgcn_cvt_pkrtz(wv.x, wv.y);
            p.h2[1] = __builtin_amdgcn_cvt_pkrtz(wv.z, wv.w);
            *(auint2*)&Ws_h[j][cq] = p.u2;
        }
        {
            int nl = t & 127, cb = (t >> 7) * 32;
            float v[32];
#pragma unroll
            for (int i = 0; i < 32; ++i)
                v[i] = A[(size_t)(c0 + cb + i) * NTOK + n0 + nl];
            if (do_am) {
#pragma unroll
                for (int i = 0; i < 32; ++i) {
                    amsum += v[i]; ammax = fmaxf(ammax, v[i]);
                }
            }
            union { h16x2 h2[16]; int4 i4[4]; } u;
#pragma unroll
            for (int m = 0; m < 16; ++m)
                u.h2[m] = __builtin_amdgcn_cvt_pkrtz(v[2 * m], v[2 * m + 1]);
#pragma unroll
            for (int m = 0; m < 4; ++m)
                *(aint4*)&Xs[nl][cb + m * 8] = u.i4[m];
        }
        __syncthreads();
        const _Float16* wA = &Ws_h[wj * 32 + (lane & 15)][(lane >> 4) * 8];
        const _Float16* xB = &Xs [wn * 64 + (lane & 15)][(lane >> 4) * 8];
#pragma unroll
        for (int s = 0; s < 2; ++s) {
            f16x8 a0 = *(const f16x8a*)(wA + s * 32);
            f16x8 a1 = *(const f16x8a*)(wA + 16 * 72 + s * 32);
            f16x8 b0 = *(const f16x8a*)(xB + s * 32);
            f16x8 b1 = *(const f16x8a*)(xB + 16 * 72 + s * 32);
            f16x8 b2 = *(const f16x8a*)(xB + 32 * 72 + s * 32);
            f16x8 b3 = *(const f16x8a*)(xB + 48 * 72 + s * 32);
            acc[0][0] = __builtin_amdgcn_mfma_f32_16x16x32_f16(a0, b0, acc[0][0], 0, 0, 0);
            acc[0][1] = __builtin_amdgcn_mfma_f32_16x16x32_f16(a0, b1, acc[0][1], 0, 0, 0);
            acc[0][2] = __builtin_amdgcn_mfma_f32_16x16x32_f16(a0, b2, acc[0][2], 0, 0, 0);
            acc[0][3] = __builtin_amdgcn_mfma_f32_16x16x32_f16(a0, b3, acc[0][3], 0, 0, 0);
            acc[1][0] = __builtin_amdgcn_mfma_f32_16x16x32_f16(a1, b0, acc[1][0], 0, 0, 0);
            acc[1][1] = __builtin_amdgcn_mfma_f32_16x16x32_f16(a1, b1, acc[1][1], 0, 0, 0);
            acc[1][2] = __builtin_amdgcn_mfma_f32_16x16x32_f16(a1, b2, acc[1][2], 0, 0, 0);
            acc[1][3] = __builtin_amdgcn_mfma_f32_16x16x32_f16(a1, b3, acc[1][3], 0, 0, 0);
        }
    }

    if (do_am) {
        int nl = t & 127, cbg = t >> 7;
        ams[0][cbg][nl] = amsum;
        ams[1][cbg][nl] = ammax;
        __syncthreads();
        if (t < 128) {
            float ss = ams[0][0][t] + ams[0][1][t];
            float mm = fmaxf(ams[1][0][t], ams[1][1][t]);
            am[(size_t)b * 2 * NTOK + n0 + t]        = ss * (1.0f / DIM);
            am[(size_t)b * 2 * NTOK + NTOK + n0 + t] = mm;
        }
    }

    const float qsc = 0.35355339059327373f * 1.4426950408889634f;
    int jb0 = j0 + wj * 32 + (lane >> 4) * 4;
    int nn0 = n0 + wn * 64 + (lane & 15);
#pragma unroll
    for (int jt = 0; jt < 2; ++jt) {
#pragma unroll
        for (int nt = 0; nt < 4; ++nt) {
            f32x4 ac = acc[jt][nt];
            int jb = jb0 + jt * 16;
            int n  = nn0 + nt * 16;
            if (jb < 256) {
                int hh = jb >> 3, dq = jb & 7;
                union { h16x2 h2[2]; uint2 u2; } p;
                p.h2[0] = __builtin_amdgcn_cvt_pkrtz(ac[0] * qsc, ac[1] * qsc);
                p.h2[1] = __builtin_amdgcn_cvt_pkrtz(ac[2] * qsc, ac[3] * qsc);
                *(auint2*)(qh + ((size_t)((b << 5) | hh) * NTOK + n) * 8 + dq) = p.u2;
            } else {
                union { h16x2 h2[2]; uint2 u2; } p;
                p.h2[0] = __builtin_amdgcn_cvt_pkrtz(ac[0], ac[1]);
                p.h2[1] = __builtin_amdgcn_cvt_pkrtz(ac[2], ac[3]);
                *(auint2*)(khv + ((size_t)b * NTOK + n) * 512 + (jb - 256)) = p.u2;
                if (jb >= 512) {
                    _Float16* vp = vt + (size_t)(b * DIM + jb - 512) * NTOK + n;
                    vp[0]        = (_Float16)ac[0];
                    vp[NTOK]     = (_Float16)ac[1];
                    vp[2 * NTOK] = (_Float16)ac[2];
                    vp[3 * NTOK] = (_Float16)ac[3];
                }
            }
        }
    }
}

// ---------------- 3+4b. fused top-512 radix-select + K/V gather per (b,h) -------
__global__ __launch_bounds__(256)
void kv_topk(const float* __restrict__ scores, const _Float16* __restrict__ khv,
             _Float16* __restrict__ kvs) {
    __shared__ int wsum[4];
    __shared__ unsigned int s_thr;
    __shared__ int s_cnt;
    __shared__ unsigned int tiem[NTOK / 32];
    __shared__ int tiep[NTOK / 32];
    __shared__ int sel[KTOP];
    int bh = blockIdx.x;           // b*32 + h
    int h = bh & 31, b = bh >> 5;
    int tid = threadIdx.x, lane = tid & 63, wid = tid >> 6;
    unsigned int v[16];
#pragma unroll
    for (int j = 0; j < 16; ++j)
        v[j] = __float_as_uint(scores[b * NTOK + j * 256 + tid]);  // positive, <1.0
    if (tid == 0) { s_thr = 0u; s_cnt = 0; }
    if (tid < NTOK / 32) tiem[tid] = 0u;
    __syncthreads();
    for (int bit = 29; bit >= 0; --bit) {
        unsigned int test = s_thr | (1u << bit);
        int c = 0;
#pragma unroll
        for (int j = 0; j < 16; ++j)
            c += (int)__popcll(__ballot(v[j] >= test));
        if (lane == 0) wsum[wid] = c;
        __syncthreads();
        if (tid == 0) {
            int tot = wsum[0] + wsum[1] + wsum[2] + wsum[3];
            if (tot >= KTOP) s_thr = test;
        }
        __syncthreads();
    }
    unsigned int T = s_thr;
    {
        int c = 0;
#pragma unroll
        for (int j = 0; j < 16; ++j)
            c += (int)__popcll(__ballot(v[j] > T));
        if (lane == 0) wsum[wid] = c;
    }
    __syncthreads();
    int cnt_gt = wsum[0] + wsum[1] + wsum[2] + wsum[3];
    int krem = KTOP - cnt_gt;
#pragma unroll
    for (int j = 0; j < 16; ++j) {
        int i = j * 256 + tid;
        if (v[j] > T) sel[atomicAdd(&s_cnt, 1)] = i;
        if (v[j] == T) atomicOr(&tiem[i >> 5], 1u << (i & 31));
    }
    __syncthreads();
    if (tid == 0) {
        int c = 0;
        for (int w2 = 0; w2 < NTOK / 32; ++w2) { tiep[w2] = c; c += __popc(tiem[w2]); }
    }
    __syncthreads();
#pragma unroll
    for (int j = 0; j < 16; ++j) {
        int i = j * 256 + tid;
        if (v[j] == T) {
            int r = tiep[i >> 5] + __popc(tiem[i >> 5] & ((1u << (i & 31)) - 1u));
            if (r < krem) sel[cnt_gt + r] = i;
        }
    }
    __syncthreads();
    aint4* dst = (aint4*)(kvs + (size_t)bh * KTOP * 16);
    const _Float16* src = khv + (size_t)b * NTOK * 512;
    for (int i = tid; i < KTOP; i += 256) {
        int tok = sel[i];
        aint4 k16 = *(const aint4*)(src + (size_t)tok * 512 + h * 8);
        aint4 v16 = *(const aint4*)(src + (size_t)tok * 512 + 256 + h * 8);
        dst[2 * i]     = k16;
        dst[2 * i + 1] = v16;
    }
}

// ---------------- 5+7. fused attention + depthwise conv (independent works) -----
// Attention PV now uses mfma_f32_16x16x16_f16: its B-fragment layout (rows
// (l>>4)*4+j, col l&15) EQUALS the QK C-layout, so exp'd P feeds PV directly
// in registers -- no P LDS round-trip.
struct AttnSm {
    _Float16 Klds[KTOP][8];        // [k][d] 16B rows
    _Float16 Vt[9][KTOP + 8];      // [d][k]; row 8 = ones (lsum trick)
};
union FusedSm { AttnSm a; float dwtile[NTOK]; };

__global__ __launch_bounds__(256)
void attn_dw(const _Float16* __restrict__ qh, const _Float16* __restrict__ kvs,
             _Float16* __restrict__ at,
             const _Float16* __restrict__ vt, const float* __restrict__ dww,
             const float* __restrict__ dwb, _Float16* __restrict__ dwo) {
    __shared__ FusedSm sm;
    int bid = blockIdx.x;
    int tid = threadIdx.x;

    if (bid < NB * DIM) {
        // ---------- depthwise 3x3x3 conv ----------
        int b = bid / DIM, c = bid % DIM;
        float* tile = sm.dwtile;
        const _Float16* src = vt + (size_t)(b * DIM + c) * NTOK;
        for (int i = tid * 8; i < NTOK; i += 2048) {
            f16x8 v8 = *(const f16x8a*)(src + i);
#pragma unroll
            for (int m = 0; m < 8; ++m) tile[i + m] = (float)v8[m];
        }
        float wreg[27];
#pragma unroll
        for (int i = 0; i < 27; ++i) wreg[i] = dww[c * 27 + i];
        float bias = dwb[c];
        __syncthreads();
        for (int i = tid; i < NTOK; i += 256) {
            int d = i >> 8, h = (i >> 4) & 15, w = i & 15;
            float acc = bias;
#pragma unroll
            for (int kd = 0; kd < 3; ++kd) {
                int dz = d + kd - 1; if (dz < 0 || dz > 15) continue;
#pragma unroll
                for (int kh = 0; kh < 3; ++kh) {
                    int hz = h + kh - 1; if (hz < 0 || hz > 15) continue;
#pragma unroll
                    for (int kw = 0; kw < 3; ++kw) {
                        int wz = w + kw - 1; if (wz < 0 || wz > 15) continue;
                        acc += tile[(dz * 16 + hz) * 16 + wz] * wreg[(kd * 3 + kh) * 3 + kw];
                    }
                }
            }
            dwo[(size_t)(b * DIM + c) * NTOK + i] = (_Float16)acc;
        }
        return;
    }

    // ---------- attention via MFMA (f16 frags, fp32 acc, ones-row lsum) ----------
    int abid = bid - NB * DIM;                // ((b*32+h)*16 + tb)
    int tb = abid & 15, bh = abid >> 4;
    int lane = tid & 63, wid = tid >> 6;

    const aint4* kvb = (const aint4*)(kvs + (size_t)bh * KTOP * 16);
    for (int i = tid; i < KTOP; i += 256) {
        int4 kk = kvb[2 * i];
        int4 vv = kvb[2 * i + 1];
        *(aint4*)&sm.a.Klds[i][0] = kk;
        union { int4 i4; unsigned short u[8]; } uv; uv.i4 = vv;
        unsigned short* vcol = (unsigned short*)&sm.a.Vt[0][0];
#pragma unroll
        for (int d = 0; d < 8; ++d)
            vcol[d * (KTOP + 8) + i] = uv.u[d];
        vcol[8 * (KTOP + 8) + i] = 0x3C00;    // f16 1.0
    }

    int qblk = tb * 256 + wid * 64;
    int qcol = lane & 15;
    const _Float16* qb = qh + (size_t)bh * NTOK * 8;
    f16x8 qf[4];
#pragma unroll
    for (int t = 0; t < 4; ++t)
        qf[t] = *(const f16x8a*)(qb + (size_t)(qblk + t * 16 + qcol) * 8);
    __syncthreads();

    int vr = lane & 15; if (vr > 8) vr = 8;             // rows 9-15 dup row 8 (C rows 9-15 unread)
    const _Float16* vrow = &sm.a.Vt[vr][(lane >> 4) * 4];

    f32x4 acc[4];
#pragma unroll
    for (int t = 0; t < 4; ++t) acc[t] = (f32x4){0.f, 0.f, 0.f, 0.f};
    const f32x4 z = {0.f, 0.f, 0.f, 0.f};

    for (int ks = 0; ks < 16; ++ks) {
        f16x8 ka = {}, kb = {};
        if (lane < 16) {
            ka = *(const f16x8a*)&sm.a.Klds[ks * 32 + lane][0];
            kb = *(const f16x8a*)&sm.a.Klds[ks * 32 + 16 + lane][0];
        }
        f16x4 va0 = *(const f16x4a*)&vrow[ks * 32];        // keys ks*32 + (g*4..+3)
        f16x4 va1 = *(const f16x4a*)&vrow[ks * 32 + 16];   // keys ks*32+16 + (g*4..+3)
#pragma unroll
        for (int t = 0; t < 4; ++t) {
            f32x4 c0 = __builtin_amdgcn_mfma_f32_16x16x32_f16(ka, qf[t], z, 0, 0, 0);
            f32x4 c1 = __builtin_amdgcn_mfma_f32_16x16x32_f16(kb, qf[t], z, 0, 0, 0);
            float p0 = __builtin_amdgcn_exp2f(c0[0]);
            float p1 = __builtin_amdgcn_exp2f(c0[1]);
            float p2 = __builtin_amdgcn_exp2f(c0[2]);
            float p3 = __builtin_amdgcn_exp2f(c0[3]);
            float p4 = __builtin_amdgcn_exp2f(c1[0]);
            float p5 = __builtin_amdgcn_exp2f(c1[1]);
            float p6 = __builtin_amdgcn_exp2f(c1[2]);
            float p7 = __builtin_amdgcn_exp2f(c1[3]);
            union { h16x2 h2[2]; f16x4 v; } u0, u1;
            u0.h2[0] = __builtin_amdgcn_cvt_pkrtz(p0, p1);
            u0.h2[1] = __builtin_amdgcn_cvt_pkrtz(p2, p3);
            u1.h2[0] = __builtin_amdgcn_cvt_pkrtz(p4, p5);
            u1.h2[1] = __builtin_amdgcn_cvt_pkrtz(p6, p7);
            acc[t] = __builtin_amdgcn_mfma_f32_16x16x16f16(va0, u0.v, acc[t], 0, 0, 0);
            acc[t] = __builtin_amdgcn_mfma_f32_16x16x16f16(va1, u1.v, acc[t], 0, 0, 0);
        }
    }

    int b = bh >> 5, h = bh & 31;
#pragma unroll
    for (int t = 0; t < 4; ++t) {
        float ls = __shfl(acc[t][0], 32 + (lane & 15));   // C row 8 = sum(p)
        float inv = 1.0f / ls;
        if (lane < 32) {
            int n = qblk + t * 16 + (lane & 15);
            int dbase = (lane >> 4) * 4;
            _Float16* op = at + ((size_t)(b * DIM + h * HDIM + dbase)) * NTOK + n;
            op[0]        = (_Float16)(acc[t][0] * inv);
            op[NTOK]     = (_Float16)(acc[t][1] * inv);
            op[2 * NTOK] = (_Float16)(acc[t][2] * inv);
            op[3 * NTOK] = (_Float16)(acc[t][3] * inv);
        }
    }
}

// ---------------- 6+8. fused proj + pw GEMM, 64j x 128n tile --------------------
__global__ __launch_bounds__(256)
void gemm_dual(const _Float16* __restrict__ At, const _Float16* __restrict__ Dw,
               const float* __restrict__ Wp_, const float* __restrict__ Wq_,
               const float* __restrict__ bp_, const float* __restrict__ bq_,
               float* __restrict__ outbase) {
    __shared__ _Float16 Wp[64][72];
    __shared__ _Float16 Wq[64][72];
    __shared__ _Float16 Xa[128][72];
    __shared__ _Float16 Xd[128][72];
    int b  = blockIdx.z;
    int j0 = blockIdx.x * 64;
    int n0 = blockIdx.y * 128;
    int t  = threadIdx.x;
    int lane = t & 63, wid = t >> 6;
    int wj = wid >> 1, wn = wid & 1;
    const _Float16* Aa = At + (size_t)b * DIM * NTOK;
    const _Float16* Ad = Dw + (size_t)b * DIM * NTOK;

    f32x4 acc[2][4];
#pragma unroll
    for (int i = 0; i < 2; ++i)
#pragma unroll
        for (int j = 0; j < 4; ++j) acc[i][j] = (f32x4){0.f, 0.f, 0.f, 0.f};

    for (int ks = 0; ks < 4; ++ks) {
        int c0 = ks * 64;
        if (ks) __syncthreads();
#pragma unroll
        for (int r = 0; r < 4; ++r) {
            int j  = r * 16 + (t >> 4);
            int cq = (t & 15) * 4;
            float4 wv = *(const float4*)(Wp_ + (size_t)(j0 + j) * DIM + c0 + cq);
            float4 wu = *(const float4*)(Wq_ + (size_t)(j0 + j) * DIM + c0 + cq);
            union { h16x2 h2[2]; uint2 u2; } p, q;
            p.h2[0] = __builtin_amdgcn_cvt_pkrtz(wv.x, wv.y);
            p.h2[1] = __builtin_amdgcn_cvt_pkrtz(wv.z, wv.w);
            q.h2[0] = __builtin_amdgcn_cvt_pkrtz(wu.x, wu.y);
            q.h2[1] = __builtin_amdgcn_cvt_pkrtz(wu.z, wu.w);
            *(auint2*)&Wp[j][cq] = p.u2;
            *(auint2*)&Wq[j][cq] = q.u2;
        }
        {
            int nl = t & 127, cb = (t >> 7) * 32;
            union { unsigned short u[32]; int4 i4[4]; } ua, ud;
#pragma unroll
            for (int i = 0; i < 32; ++i) {
                ua.u[i] = *(const unsigned short*)(Aa + (size_t)(c0 + cb + i) * NTOK + n0 + nl);
                ud.u[i] = *(const unsigned short*)(Ad + (size_t)(c0 + cb + i) * NTOK + n0 + nl);
            }
#pragma unroll
            for (int m = 0; m < 4; ++m) {
                *(aint4*)&Xa[nl][cb + m * 8] = ua.i4[m];
                *(aint4*)&Xd[nl][cb + m * 8] = ud.i4[m];
            }
        }
        __syncthreads();
        const _Float16* wPa = &Wp[wj * 32 + (lane & 15)][(lane >> 4) * 8];
        const _Float16* wQa = &Wq[wj * 32 + (lane & 15)][(lane >> 4) * 8];
        const _Float16* xAa = &Xa[wn * 64 + (lane & 15)][(lane >> 4) * 8];
        const _Float16* xDa = &Xd[wn * 64 + (lane & 15)][(lane >> 4) * 8];
#pragma unroll
        for (int s = 0; s < 2; ++s) {
            f16x8 p0 = *(const f16x8a*)(wPa + s * 32);
            f16x8 p1 = *(const f16x8a*)(wPa + 16 * 72 + s * 32);
            f16x8 q0 = *(const f16x8a*)(wQa + s * 32);
            f16x8 q1 = *(const f16x8a*)(wQa + 16 * 72 + s * 32);
#pragma unroll
            for (int nt = 0; nt < 4; ++nt) {
                f16x8 a = *(const f16x8a*)(xAa + nt * 16 * 72 + s * 32);
                f16x8 d = *(const f16x8a*)(xDa + nt * 16 * 72 + s * 32);
                acc[0][nt] = __builtin_amdgcn_mfma_f32_16x16x32_f16(p0, a, acc[0][nt], 0, 0, 0);
                acc[0][nt] = __builtin_amdgcn_mfma_f32_16x16x32_f16(q0, d, acc[0][nt], 0, 0, 0);
                acc[1][nt] = __builtin_amdgcn_mfma_f32_16x16x32_f16(p1, a, acc[1][nt], 0, 0, 0);
                acc[1][nt] = __builtin_amdgcn_mfma_f32_16x16x32_f16(q1, d, acc[1][nt], 0, 0, 0);
            }
        }
    }

    int jb0 = j0 + wj * 32 + (lane >> 4) * 4;
    int nn0 = n0 + wn * 64 + (lane & 15);
#pragma unroll
    for (int jt = 0; jt < 2; ++jt) {
#pragma unroll
        for (int nt = 0; nt < 4; ++nt) {
            f32x4 ac = acc[jt][nt];
            int jb = jb0 + jt * 16;
            int n  = nn0 + nt * 16;
            float4 bp = *(const float4*)(bp_ + jb);
            float4 bq = *(const float4*)(bq_ + jb);
            float* op = outbase + (size_t)(b * DIM + jb) * NTOK + n;
            op[0]        = ac[0] + bp.x + bq.x;
            op[NTOK]     = ac[1] + bp.y + bq.y;
            op[2 * NTOK] = ac[2] + bp.z + bq.z;
            op[3 * NTOK] = ac[3] + bp.w + bq.w;
        }
    }
}

extern "C" void kernel_launch(void* const* d_in, const int* in_sizes, int n_in,
                              void* d_out, int out_size, void* d_ws, size_t ws_size,
                              hipStream_t stream) {
    const float* x      = (const float*)d_in[0];
    const float* spa_w  = (const float*)d_in[1];
    const float* qkv_w  = (const float*)d_in[2];
    const float* proj_w = (const float*)d_in[3];
    const float* proj_b = (const float*)d_in[4];
    const float* dw_w   = (const float*)d_in[5];
    const float* dw_b   = (const float*)d_in[6];
    const float* pw_w   = (const float*)d_in[7];
    const float* pw_b   = (const float*)d_in[8];
    float* out = (float*)d_out;
    float* ws  = (float*)d_ws;

    float* am      = ws + AM_OFF;
    float* scores  = ws + SC_OFF;
    _Float16* vth  = (_Float16*)(ws + VT_OFF);
    _Float16* ath  = (_Float16*)(ws + AT_OFF);
    _Float16* dwh  = (_Float16*)(ws + DW_OFF);
    _Float16* kvs  = (_Float16*)(ws + KVS_OFF);
    _Float16* khv  = (_Float16*)(ws + KHV_OFF);
    _Float16* qh   = (_Float16*)(ws + QH_OFF);

    gemm_qkv<<<dim3(12, 32, NB), 256, 0, stream>>>(x, qkv_w, khv, vth, qh, am);
    spa_conv<<<NB * 16, 256, 0, stream>>>(am, spa_w, scores);
    kv_topk<<<NB * NHEAD, 256, 0, stream>>>(scores, khv, kvs);
    attn_dw<<<NB * DIM + NB * NHEAD * 16, 256, 0, stream>>>(qh, kvs, ath,
                                                            vth, dw_w, dw_b, dwh);
    gemm_dual<<<dim3(4, 32, NB), 256, 0, stream>>>(ath, dwh, proj_w, pw_w,
                                                   proj_b, pw_b, out);
}